// Round 2
// baseline (7601.056 us; speedup 1.0000x reference)
//
#include <hip/hip_runtime.h>
#include <math.h>

// ---------------------------------------------------------------------------
// STAttentionRecBlock fp32, sample-chunked (G samples/pass, G from ws_size).
// 8 logical samples: 0..3 = x, 4..7 = x1. Output flat: sample ns at ns*SAMP.
// R3: temporal in-GEMM writes transposed qkT (MODE 5); scores_t = tiled GEMM.
// R4: scores_s re-chunked 8->200 blocks/(s,ln).
// R5: pipelined K-loops (dbuf+prefetch). Neutral: bottleneck is LDS read BW,
//     not latency (VALUBusy 53-59% == 4x(2x19+2x12)/128 = 1.94x LDS overcommit).
// R6: 8x16 per-thread tile (BM=128, BN=256) in gemm_conv/apply_t: 6 b128 per
//     128 FMA (was 4 per 64) -> LDS demand 1.13x; quartered row/col slices
//     (ty*4 / 64+ty*4, q*64+tx*4) -> all LDS reads 2-way max (free).
//     apply_t Y-staging re-mapped lane-consecutive (coalesced + conflict-free).
// Workspace per chunk-sample: A 3.84M f | Zs 2.56M f | aT 0.48M f | sp 15000
//   | as 1875 = 27,587,500 B per G. G adaptive in {8,4,2,1}.
// ---------------------------------------------------------------------------

#define PP 10000          // T*V
#define SAMP 2560000      // C*PP
#define BM 128
#define BN 256
#define BKc 8

__device__ __forceinline__ float4 ld4(const float* p) { return *(const float4*)p; }
__device__ __forceinline__ float lrelu(float v) { return v >= 0.f ? v : 0.1f * v; }

// ---------------------------------------------------------------------------
// Tiled conv-as-GEMM over a chunk. blockIdx.z = ln (chunk-local sample).
// MODE 0: out = acc + bias
// MODE 1: out = lrelu(res + g*(acc+bias) + beta)            (ff)
// MODE 2: out = acc                                         (out-gemm s=0)
// MODE 3: out += acc                                        (out-gemm s=1)
// MODE 4: out = lrelu(res + g*(out + acc + bias) + beta)    (out-gemm s=2)
// MODE 5: out = acc + bias, written as qkT[sec][t][v*64+cl] (temporal in-gemm)
// Thread tile: rows {m0+ty*4+0..3, m0+64+ty*4+0..3}, cols {p0+q*64+tx*4+0..3}.
// ---------------------------------------------------------------------------
template<int MODE, bool PE, bool BGLOB, bool OUTGLOB>
__global__ __launch_bounds__(256, 2)
void gemm_conv(const float* __restrict__ W, int Kw,
               const float* __restrict__ bias,
               const float* __restrict__ g, const float* __restrict__ beta,
               const float* __restrict__ bg0, const float* __restrict__ bg1,
               const float* __restrict__ bw,
               const float* __restrict__ pe,
               const float* rg0, const float* rg1,
               float* out, int n0, int M, int K)
{
    const int ln = blockIdx.z;
    const int ns = n0 + ln;
    const int p0 = blockIdx.x * BN;
    const int m0 = blockIdx.y * BM;
    const int tid = threadIdx.x;
    const int tx = tid & 15, ty = tid >> 4;

    const float* Bp;
    if (BGLOB)
        Bp = (ns < 4) ? bg0 + (size_t)ns * (size_t)K * PP
                      : bg1 + (size_t)(ns - 4) * (size_t)K * PP;
    else
        Bp = bw + (size_t)ln * (size_t)K * PP;

    __shared__ float As[2][BKc][BM + 4];
    __shared__ float Bs[2][BKc][BN + 8];

    float acc[8][16];
#pragma unroll
    for (int i = 0; i < 8; i++)
#pragma unroll
        for (int j = 0; j < 16; j++) acc[i][j] = 0.f;

    const int ar = tid >> 1;        // A row in M-tile (0..127)
    const int ak = (tid & 1) * 4;   // A k offset (0 or 4)
    const int bk = tid >> 5;        // B k row (0..7)
    const int bc = (tid & 31) * 8;  // B col (0..248)
    const bool fullN = (p0 + BN <= PP);

    auto loadB = [&](int kc, float* bv) {
        if (fullN) {
            float4 t0 = ld4(&Bp[(size_t)(kc + bk) * PP + p0 + bc]);
            float4 t1 = ld4(&Bp[(size_t)(kc + bk) * PP + p0 + bc + 4]);
            bv[0] = t0.x; bv[1] = t0.y; bv[2] = t0.z; bv[3] = t0.w;
            bv[4] = t1.x; bv[5] = t1.y; bv[6] = t1.z; bv[7] = t1.w;
            if (PE) {
                float4 p0v = ld4(&pe[(size_t)(kc + bk) * PP + p0 + bc]);
                float4 p1v = ld4(&pe[(size_t)(kc + bk) * PP + p0 + bc + 4]);
                bv[0] += p0v.x; bv[1] += p0v.y; bv[2] += p0v.z; bv[3] += p0v.w;
                bv[4] += p1v.x; bv[5] += p1v.y; bv[6] += p1v.z; bv[7] += p1v.w;
            }
        } else {
#pragma unroll
            for (int e = 0; e < 8; e++) {
                int p = p0 + bc + e;
                float v = 0.f;
                if (p < PP) {
                    v = Bp[(size_t)(kc + bk) * PP + p];
                    if (PE) v += pe[(size_t)(kc + bk) * PP + p];
                }
                bv[e] = v;
            }
        }
    };

    // prefetch K-chunk 0
    float4 av = ld4(&W[(size_t)(m0 + ar) * Kw + ak]);
    float bv[8];
    loadB(0, bv);

    int buf = 0;
#pragma unroll 2
    for (int k0 = 0; k0 < K; k0 += BKc) {
        As[buf][ak + 0][ar] = av.x;
        As[buf][ak + 1][ar] = av.y;
        As[buf][ak + 2][ar] = av.z;
        As[buf][ak + 3][ar] = av.w;
        *(float4*)&Bs[buf][bk][bc]     = make_float4(bv[0], bv[1], bv[2], bv[3]);
        *(float4*)&Bs[buf][bk][bc + 4] = make_float4(bv[4], bv[5], bv[6], bv[7]);
        __syncthreads();
        const int kn = k0 + BKc;
        if (kn < K) {
            av = ld4(&W[(size_t)(m0 + ar) * Kw + kn + ak]);
            loadB(kn, bv);
        }
#pragma unroll
        for (int kk = 0; kk < BKc; kk++) {
            float4 a0 = ld4(&As[buf][kk][ty * 4]);
            float4 a1 = ld4(&As[buf][kk][64 + ty * 4]);
            float4 b0 = ld4(&Bs[buf][kk][tx * 4]);
            float4 b1 = ld4(&Bs[buf][kk][64 + tx * 4]);
            float4 b2 = ld4(&Bs[buf][kk][128 + tx * 4]);
            float4 b3 = ld4(&Bs[buf][kk][192 + tx * 4]);
            float aR[8] = {a0.x, a0.y, a0.z, a0.w, a1.x, a1.y, a1.z, a1.w};
            float bR[16] = {b0.x, b0.y, b0.z, b0.w, b1.x, b1.y, b1.z, b1.w,
                            b2.x, b2.y, b2.z, b2.w, b3.x, b3.y, b3.z, b3.w};
#pragma unroll
            for (int i = 0; i < 8; i++)
#pragma unroll
                for (int j = 0; j < 16; j++)
                    acc[i][j] = fmaf(aR[i], bR[j], acc[i][j]);
        }
        buf ^= 1;
    }

    if (MODE == 5) {
        // Transposed write: qkT[ln][sec][t][v*64 + cl].
        // Row group A: m0+ty*4+0..3 (sec m0>>6), group B: m0+64+ty*4 (sec+1).
        const int mA = m0 + ty * 4;
        const int mB = mA + 64;
        const int clA = mA & 63;        // == ty*4
        float* qtA = out + (size_t)ln * 3840000ull + (size_t)(mA >> 6) * 640000ull + clA;
        float* qtB = out + (size_t)ln * 3840000ull + (size_t)(mB >> 6) * 640000ull + clA;
        float biA[4], biB[4];
#pragma unroll
        for (int i = 0; i < 4; i++) { biA[i] = bias[mA + i]; biB[i] = bias[mB + i]; }
#pragma unroll
        for (int q = 0; q < 4; q++) {
#pragma unroll
            for (int jj = 0; jj < 4; jj++) {
                int p = p0 + q * 64 + tx * 4 + jj;
                if (p >= PP) continue;
                int t = p / 25, v = p - t * 25;
                size_t off = (size_t)t * 1600 + v * 64;
                int cj = q * 4 + jj;
                *(float4*)(qtA + off) = make_float4(acc[0][cj] + biA[0], acc[1][cj] + biA[1],
                                                    acc[2][cj] + biA[2], acc[3][cj] + biA[3]);
                *(float4*)(qtB + off) = make_float4(acc[4][cj] + biB[0], acc[5][cj] + biB[1],
                                                    acc[6][cj] + biB[2], acc[7][cj] + biB[3]);
            }
        }
        return;
    }

    float* op = out + (OUTGLOB ? (size_t)ns : (size_t)ln) * (size_t)M * PP;
    const float* resp = nullptr;
    if (MODE == 1 || MODE == 4)
        resp = (ns < 4) ? rg0 + (size_t)ns * SAMP : rg1 + (size_t)(ns - 4) * SAMP;

#pragma unroll
    for (int i = 0; i < 8; i++) {
        int m = (i < 4) ? (m0 + ty * 4 + i) : (m0 + 64 + ty * 4 + (i - 4));
        float bi = (MODE == 0 || MODE == 1 || MODE == 4) ? bias[m] : 0.f;
        float gi = (MODE == 1 || MODE == 4) ? g[m] : 0.f;
        float be = (MODE == 1 || MODE == 4) ? beta[m] : 0.f;
        size_t rowoff = (size_t)m * PP;
#pragma unroll
        for (int q = 0; q < 4; q++) {
            int pb = p0 + q * 64 + tx * 4;
#pragma unroll
            for (int jj = 0; jj < 4; jj++) {
                int p = pb + jj;
                if (!fullN && p >= PP) continue;
                float a = acc[i][q * 4 + jj];
                float val;
                if (MODE == 0)      val = a + bi;
                else if (MODE == 2) val = a;
                else if (MODE == 3) val = op[rowoff + p] + a;
                else if (MODE == 4) val = lrelu(resp[rowoff + p] + gi * (op[rowoff + p] + a + bi) + be);
                else                val = lrelu(resp[rowoff + p] + gi * (a + bi) + be);
                op[rowoff + p] = val;
            }
        }
    }
}

// ---------------------------------------------------------------------------
// Spatial scores, partial K (R4): 200 chunks of 128 rows. Grid (200, 3, G).
// ---------------------------------------------------------------------------
__global__ __launch_bounds__(256)
void scores_s_partial(const float* __restrict__ qk, float* __restrict__ part)
{
    const int chunk = blockIdx.x, s = blockIdx.y, ln = blockIdx.z;
    const float* qsec = qk + ((size_t)ln * 384 + s * 64) * PP + (size_t)chunk * 3200;
    const float* ksec = qk + ((size_t)ln * 384 + (3 + s) * 64) * PP + (size_t)chunk * 3200;
    __shared__ float QL[3200];
    __shared__ float KL[3200];
    const int tid = threadIdx.x;
    for (int i = tid; i < 3200; i += 256) {
        QL[i] = qsec[i];
        KL[i] = ksec[i];
    }
    __syncthreads();
    const int o0 = tid, o1 = tid + 256, o2 = tid + 512;
    const int u0 = o0 / 25, v0 = o0 % 25;
    const int u1 = o1 / 25, v1 = o1 % 25;
    const int u2 = o2 / 25, v2 = o2 % 25;
    float a0 = 0.f, a1 = 0.f, a2 = 0.f;
#pragma unroll 8
    for (int r = 0; r < 128; r++) {
        int ro = r * 25;
        a0 = fmaf(QL[ro + u0], KL[ro + v0], a0);
        a1 = fmaf(QL[ro + u1], KL[ro + v1], a1);
        if (tid < 113) a2 = fmaf(QL[ro + u2], KL[ro + v2], a2);
    }
    float* pp = part + (((size_t)(ln * 3 + s)) * 200 + chunk) * 625;
    pp[o0] = a0;
    pp[o1] = a1;
    if (tid < 113) pp[o2] = a2;
}

// grid.x = 3*G blocks (idx = ln*3+s), 640 threads. Sums 200 partials.
__global__ void scores_s_final(const float* __restrict__ part,
                               const float* __restrict__ alphas,
                               const float* __restrict__ att0s,
                               float* __restrict__ atts)
{
    const int idx = blockIdx.x;
    const int s = idx % 3;
    const int o = threadIdx.x;
    if (o >= 625) return;
    const float* pb = part + (size_t)idx * 200 * 625 + o;
    float sum = 0.f;
#pragma unroll 8
    for (int i = 0; i < 200; i++) sum += pb[(size_t)i * 625];
    atts[(size_t)idx * 625 + o] = tanhf(sum * (1.f / 25600.f)) * alphas[s] + att0s[s * 625 + o];
}

// ---------------------------------------------------------------------------
// Spatial apply (one s): z[ln][c][t][w] = sum_v x[ns][c][t][v] * atts[ln][s][v][w]
// Grid (200, G). Thread owns 2 consecutive rows r=(c*400+t).
// ---------------------------------------------------------------------------
__global__ __launch_bounds__(256)
void apply_s_kernel(const float* __restrict__ x0, const float* __restrict__ x1,
                    const float* __restrict__ atts, float* __restrict__ z,
                    int n0, int s)
{
    const int ln = blockIdx.y;
    const int ns = n0 + ln;
    const int tid = threadIdx.x;
    __shared__ float attL[700];   // 25*28 padded
    for (int i = tid; i < 700; i += 256) attL[i] = 0.f;
    __syncthreads();
    for (int i = tid; i < 625; i += 256) {
        int v = i / 25, w = i % 25;
        attL[v * 28 + w] = atts[(size_t)ln * 1875 + s * 625 + i];
    }
    __syncthreads();
    const float* xp = (ns < 4) ? x0 + (size_t)ns * SAMP : x1 + (size_t)(ns - 4) * SAMP;
    const int r0 = (blockIdx.x * 256 + tid) * 2;   // even; both rows share c
    const float* xr0 = xp + (size_t)r0 * 25;
    float xr[2][25];
#pragma unroll
    for (int i = 0; i < 2; i++)
#pragma unroll
        for (int v = 0; v < 25; v++) xr[i][v] = xr0[i * 25 + v];
    const int c0 = r0 / 400, t0 = r0 % 400;

    float4 acc0[7], acc1[7];
#pragma unroll
    for (int w4 = 0; w4 < 7; w4++) {
        acc0[w4] = make_float4(0.f, 0.f, 0.f, 0.f);
        acc1[w4] = make_float4(0.f, 0.f, 0.f, 0.f);
    }
#pragma unroll
    for (int v = 0; v < 25; v++) {
        const float4* arow = (const float4*)&attL[v * 28];
        float xv0 = xr[0][v], xv1 = xr[1][v];
#pragma unroll
        for (int w4 = 0; w4 < 7; w4++) {
            float4 a = arow[w4];
            acc0[w4].x = fmaf(xv0, a.x, acc0[w4].x);
            acc0[w4].y = fmaf(xv0, a.y, acc0[w4].y);
            acc0[w4].z = fmaf(xv0, a.z, acc0[w4].z);
            acc0[w4].w = fmaf(xv0, a.w, acc0[w4].w);
            acc1[w4].x = fmaf(xv1, a.x, acc1[w4].x);
            acc1[w4].y = fmaf(xv1, a.y, acc1[w4].y);
            acc1[w4].z = fmaf(xv1, a.z, acc1[w4].z);
            acc1[w4].w = fmaf(xv1, a.w, acc1[w4].w);
        }
    }
    float* zp = z + (size_t)ln * SAMP + (size_t)c0 * PP + (size_t)t0 * 25;
#pragma unroll
    for (int w4 = 0; w4 < 7; w4++) {
        int wb = w4 * 4;
        if (wb + 0 < 25) zp[wb + 0] = acc0[w4].x;
        if (wb + 1 < 25) zp[wb + 1] = acc0[w4].y;
        if (wb + 2 < 25) zp[wb + 2] = acc0[w4].z;
        if (wb + 3 < 25) zp[wb + 3] = acc0[w4].w;
    }
#pragma unroll
    for (int w4 = 0; w4 < 7; w4++) {
        int wb = w4 * 4;
        if (wb + 0 < 25) zp[25 + wb + 0] = acc1[w4].x;
        if (wb + 1 < 25) zp[25 + wb + 1] = acc1[w4].y;
        if (wb + 2 < 25) zp[25 + wb + 2] = acc1[w4].z;
        if (wb + 3 < 25) zp[25 + wb + 3] = acc1[w4].w;
    }
}

// ---------------------------------------------------------------------------
// Temporal scores GEMM: part[(idx*2+ks)][q][t] = sum_{k in half ks}
//   qkT[ln][3+s][q][k] * qkT[ln][s][t][k].   64x64 tile, 4x4/thread, K=800.
// Grid (49, 2, 3*G). Double-buffered LDS + prefetch.
// ---------------------------------------------------------------------------
__global__ __launch_bounds__(256)
void scores_t_gemm(const float* __restrict__ qkT, float* __restrict__ part)
{
    const int idx = blockIdx.z;
    const int s = idx % 3, ln = idx / 3;
    const int ks = blockIdx.y;
    const int q0 = (blockIdx.x / 7) * 64, t0 = (blockIdx.x % 7) * 64;
    const float* base = qkT + (size_t)ln * 3840000ull;
    const float* Aq = base + (size_t)(3 + s) * 640000ull;   // rows = q
    const float* Bt = base + (size_t)s * 640000ull;         // rows = t
    __shared__ float SB[2][2][8][68];   // [buf][A/B][k][row]
    const int tid = threadIdx.x, tx = tid & 15, ty = tid >> 4;
    float acc[4][4];
#pragma unroll
    for (int i = 0; i < 4; i++)
#pragma unroll
        for (int j = 0; j < 4; j++) acc[i][j] = 0.f;

    const int half = tid >> 7;          // 0 -> stage A, 1 -> stage B
    const int r = (tid & 127) >> 1;     // 0..63 tile row
    const int ak = (tid & 1) * 4;       // k offset 0/4
    const int row = (half ? t0 : q0) + r;
    const bool rok = row < 400;
    const float* srow = (half ? Bt : Aq) + (size_t)row * 1600 + ks * 800 + ak;
    float* dL0 = &SB[0][half][0][0] + ak * 68 + r;

    float4 v = make_float4(0.f, 0.f, 0.f, 0.f);
    if (rok) v = ld4(srow);

    int buf = 0;
#pragma unroll 2
    for (int k0 = 0; k0 < 800; k0 += 8) {
        float* dL = dL0 + buf * (2 * 8 * 68);
        dL[0] = v.x; dL[68] = v.y; dL[136] = v.z; dL[204] = v.w;
        __syncthreads();
        const int kn = k0 + 8;
        if (kn < 800) {
            if (rok) v = ld4(srow + kn);
        }
#pragma unroll
        for (int kk = 0; kk < 8; kk++) {
            float4 a = ld4(&SB[buf][0][kk][ty * 4]);
            float4 b = ld4(&SB[buf][1][kk][tx * 4]);
            float aR[4] = {a.x, a.y, a.z, a.w};
            float bR[4] = {b.x, b.y, b.z, b.w};
#pragma unroll
            for (int i = 0; i < 4; i++)
#pragma unroll
                for (int j = 0; j < 4; j++)
                    acc[i][j] = fmaf(aR[i], bR[j], acc[i][j]);
        }
        buf ^= 1;
    }

    float* pp_ = part + ((size_t)idx * 2 + ks) * 160000ull;
#pragma unroll
    for (int i = 0; i < 4; i++) {
        int q = q0 + ty * 4 + i;
        if (q >= 400) continue;
        int t = t0 + tx * 4;
        if (t + 3 < 400) {
            *(float4*)&pp_[(size_t)q * 400 + t] =
                make_float4(acc[i][0], acc[i][1], acc[i][2], acc[i][3]);
        } else {
#pragma unroll
            for (int j = 0; j < 4; j++)
                if (t + j < 400) pp_[(size_t)q * 400 + t + j] = acc[i][j];
        }
    }
}

// part0+part1 -> tanh -> aT[idx][q][t].  Grid (625, 3*G), 256 threads.
__global__ void scores_t_final(const float* __restrict__ part,
                               const float* __restrict__ alphat,
                               const float* __restrict__ att0t,
                               float* __restrict__ aT)
{
    const int idx = blockIdx.y;
    const int s = idx % 3;
    const int o = blockIdx.x * 256 + threadIdx.x;   // q*400+t
    const int q = o / 400, t = o - q * 400;
    float sum = part[(size_t)(idx * 2) * 160000ull + o]
              + part[(size_t)(idx * 2 + 1) * 160000ull + o];
    aT[(size_t)idx * 160000ull + o] =
        tanhf(sum * (1.f / 1600.f)) * alphat[s] + att0t[((size_t)s * 400 + t) * 400 + q];
}

// ---------------------------------------------------------------------------
// Temporal apply (one s): z[ln][c][q][v] = sum_t attT[(ln*3+s)][q][t]*y[ns][c][t][v]
// Grid (25, 4, G): M=q (400), N=j=(c*25+v) (6400), K=t (400). BN=256, 8x16/thr.
// B staging: lane-consecutive j (coalesced global, conflict-free LDS writes).
// ---------------------------------------------------------------------------
__global__ __launch_bounds__(256, 2)
void apply_t_kernel(const float* __restrict__ y, const float* __restrict__ attT,
                    float* __restrict__ z, int n0, int s)
{
    const int ln = blockIdx.z;
    const int ns = n0 + ln;
    const int j0 = blockIdx.x * BN;
    const int q0 = blockIdx.y * BM;
    const float* A = attT + ((size_t)ln * 3 + s) * 160000;
    const float* Y = y + (size_t)ns * SAMP;
    float* zout = z + (size_t)ln * SAMP;
    __shared__ float As[2][BKc][BM + 4];
    __shared__ float Bs[2][BKc][BN + 8];
    const int tid = threadIdx.x, tx = tid & 15, ty = tid >> 4;
    const int ar = tid >> 1, ak = (tid & 1) * 4;
    const int bk = tid >> 5;        // k row 0..7
    const int bl = tid & 31;        // lane-consecutive col base
    int cB[8], vB[8];
#pragma unroll
    for (int e = 0; e < 8; e++) {
        int j = j0 + bl + 32 * e;
        cB[e] = j / 25; vB[e] = j % 25;
    }
    float acc[8][16];
#pragma unroll
    for (int i = 0; i < 8; i++)
#pragma unroll
        for (int j = 0; j < 16; j++) acc[i][j] = 0.f;
    const int qA = q0 + ar;

    // prefetch K-chunk 0
    float4 av = make_float4(0.f, 0.f, 0.f, 0.f);
    if (qA < 400) av = ld4(&A[(size_t)qA * 400 + ak]);
    float bload[8];
#pragma unroll
    for (int e = 0; e < 8; e++)
        bload[e] = Y[(size_t)cB[e] * PP + (size_t)bk * 25 + vB[e]];

    int buf = 0;
#pragma unroll 2
    for (int k0 = 0; k0 < 400; k0 += BKc) {
        As[buf][ak + 0][ar] = av.x;
        As[buf][ak + 1][ar] = av.y;
        As[buf][ak + 2][ar] = av.z;
        As[buf][ak + 3][ar] = av.w;
#pragma unroll
        for (int e = 0; e < 8; e++)
            Bs[buf][bk][bl + 32 * e] = bload[e];
        __syncthreads();
        const int kn = k0 + BKc;
        if (kn < 400) {
            av = make_float4(0.f, 0.f, 0.f, 0.f);
            if (qA < 400) av = ld4(&A[(size_t)qA * 400 + kn + ak]);
#pragma unroll
            for (int e = 0; e < 8; e++)
                bload[e] = Y[(size_t)cB[e] * PP + (size_t)(kn + bk) * 25 + vB[e]];
        }
#pragma unroll
        for (int kk = 0; kk < BKc; kk++) {
            float4 a0 = ld4(&As[buf][kk][ty * 4]);
            float4 a1 = ld4(&As[buf][kk][64 + ty * 4]);
            float4 b0 = ld4(&Bs[buf][kk][tx * 4]);
            float4 b1 = ld4(&Bs[buf][kk][64 + tx * 4]);
            float4 b2 = ld4(&Bs[buf][kk][128 + tx * 4]);
            float4 b3 = ld4(&Bs[buf][kk][192 + tx * 4]);
            float aR[8] = {a0.x, a0.y, a0.z, a0.w, a1.x, a1.y, a1.z, a1.w};
            float bR[16] = {b0.x, b0.y, b0.z, b0.w, b1.x, b1.y, b1.z, b1.w,
                            b2.x, b2.y, b2.z, b2.w, b3.x, b3.y, b3.z, b3.w};
#pragma unroll
            for (int i = 0; i < 8; i++)
#pragma unroll
                for (int j = 0; j < 16; j++)
                    acc[i][j] = fmaf(aR[i], bR[j], acc[i][j]);
        }
        buf ^= 1;
    }

    int cS[16], vS[16];
#pragma unroll
    for (int q = 0; q < 4; q++)
#pragma unroll
        for (int jj = 0; jj < 4; jj++) {
            int j = j0 + q * 64 + tx * 4 + jj;
            cS[q * 4 + jj] = j / 25; vS[q * 4 + jj] = j % 25;
        }
#pragma unroll
    for (int i = 0; i < 8; i++) {
        int q = (i < 4) ? (q0 + ty * 4 + i) : (q0 + 64 + ty * 4 + (i - 4));
        if (q >= 400) continue;
#pragma unroll
        for (int jj = 0; jj < 16; jj++)
            zout[(size_t)cS[jj] * PP + (size_t)q * 25 + vS[jj]] = acc[i][jj];
    }
}

// ---------------------------------------------------------------------------
extern "C" void kernel_launch(void* const* d_in, const int* in_sizes, int n_in,
                              void* d_out, int out_size, void* d_ws, size_t ws_size,
                              hipStream_t stream)
{
    const float* x    = (const float*)d_in[0];
    const float* x1   = (const float*)d_in[1];
    const float* pe_s = (const float*)d_in[2];
    const float* pe_t = (const float*)d_in[3];
    const float* Wsi  = (const float*)d_in[4];
    const float* bsi  = (const float*)d_in[5];
    const float* alphas = (const float*)d_in[6];
    const float* att0s  = (const float*)d_in[7];
    const float* Wso  = (const float*)d_in[8];
    const float* bso  = (const float*)d_in[9];
    const float* gso  = (const float*)d_in[10];
    const float* beso = (const float*)d_in[11];
    const float* Wsf  = (const float*)d_in[12];
    const float* bsf  = (const float*)d_in[13];
    const float* gsf  = (const float*)d_in[14];
    const float* besf = (const float*)d_in[15];
    const float* Wti  = (const float*)d_in[16];
    const float* bti  = (const float*)d_in[17];
    const float* alphat = (const float*)d_in[18];
    const float* att0t  = (const float*)d_in[19];
    const float* Wto  = (const float*)d_in[20];
    const float* bto  = (const float*)d_in[21];
    const float* gto  = (const float*)d_in[22];
    const float* beto = (const float*)d_in[23];
    const float* Wtf  = (const float*)d_in[24];
    const float* btf  = (const float*)d_in[25];
    const float* gtf  = (const float*)d_in[26];
    const float* betf = (const float*)d_in[27];

    float* outp = (float*)d_out;
    const float* outpB = outp + 4ull * SAMP;   // samples 4..7 view

    int G = 1;
    for (int g = 8; g >= 1; g >>= 1) {
        if ((size_t)g * 27587500ull <= ws_size) { G = g; break; }
    }

    float* A   = (float*)d_ws;                       // qk / qkT, then h overlay
    float* Zs  = A  + (size_t)G * 3840000ull;        // z slice / score partials
    float* aT  = Zs + (size_t)G * 2560000ull;        // temporal att
    float* sp  = aT + (size_t)G * 480000ull;         // (unused, kept for layout)
    float* as  = sp + (size_t)G * 15000ull;          // spatial att

    dim3 blk(256);
    for (int n0 = 0; n0 < 8; n0 += G) {
        dim3 gIn(40, 3, G), gOut(40, 2, G);

        // ---- spatial stage (input x / x1) ----
        gemm_conv<0, true, true, false><<<gIn, blk, 0, stream>>>(
            Wsi, 256, bsi, nullptr, nullptr, x, x1, nullptr, pe_s,
            nullptr, nullptr, A, n0, 384, 256);
        scores_s_partial<<<dim3(200, 3, G), blk, 0, stream>>>(A, Zs);
        scores_s_final<<<dim3(3 * G), dim3(640), 0, stream>>>(Zs, alphas, att0s, as);
        for (int s = 0; s < 3; s++) {
            apply_s_kernel<<<dim3(200, G), blk, 0, stream>>>(x, x1, as, Zs, n0, s);
            if (s == 0)
                gemm_conv<2, false, false, false><<<gOut, blk, 0, stream>>>(
                    Wso + s * 256, 768, nullptr, nullptr, nullptr, nullptr, nullptr, Zs,
                    nullptr, nullptr, nullptr, A, n0, 256, 256);
            else if (s == 1)
                gemm_conv<3, false, false, false><<<gOut, blk, 0, stream>>>(
                    Wso + s * 256, 768, nullptr, nullptr, nullptr, nullptr, nullptr, Zs,
                    nullptr, nullptr, nullptr, A, n0, 256, 256);
            else
                gemm_conv<4, false, false, false><<<gOut, blk, 0, stream>>>(
                    Wso + s * 256, 768, bso, gso, beso, nullptr, nullptr, Zs,
                    nullptr, x, x1, A, n0, 256, 256);
        }
        gemm_conv<1, false, false, true><<<gOut, blk, 0, stream>>>(
            Wsf, 256, bsf, gsf, besf, nullptr, nullptr, A, nullptr,
            x, x1, outp, n0, 256, 256);

        // ---- temporal stage (input d_out, in place) ----
        gemm_conv<5, true, true, false><<<gIn, blk, 0, stream>>>(
            Wti, 256, bti, nullptr, nullptr, outp, outpB, nullptr, pe_t,
            nullptr, nullptr, A, n0, 384, 256);
        scores_t_gemm<<<dim3(49, 2, 3 * G), blk, 0, stream>>>(A, Zs);
        scores_t_final<<<dim3(625, 3 * G), blk, 0, stream>>>(Zs, alphat, att0t, aT);
        for (int s = 0; s < 3; s++) {
            apply_t_kernel<<<dim3(25, 4, G), blk, 0, stream>>>(outp, aT, Zs, n0, s);
            if (s == 0)
                gemm_conv<2, false, false, false><<<gOut, blk, 0, stream>>>(
                    Wto + s * 256, 768, nullptr, nullptr, nullptr, nullptr, nullptr, Zs,
                    nullptr, nullptr, nullptr, A, n0, 256, 256);
            else if (s == 1)
                gemm_conv<3, false, false, false><<<gOut, blk, 0, stream>>>(
                    Wto + s * 256, 768, nullptr, nullptr, nullptr, nullptr, nullptr, Zs,
                    nullptr, nullptr, nullptr, A, n0, 256, 256);
            else
                gemm_conv<4, false, false, false><<<gOut, blk, 0, stream>>>(
                    Wto + s * 256, 768, bto, gto, beto, nullptr, nullptr, Zs,
                    nullptr, outp, outpB, A, n0, 256, 256);
        }
        gemm_conv<1, false, false, true><<<gOut, blk, 0, stream>>>(
            Wtf, 256, btf, gtf, betf, nullptr, nullptr, A, nullptr,
            outp, outpB, outp, n0, 256, 256);
    }
}

// Round 3
// 2677.310 us; speedup vs baseline: 2.8391x; 2.8391x over previous
//
#include <hip/hip_runtime.h>
#include <math.h>

// ---------------------------------------------------------------------------
// STAttentionRecBlock, sample-chunked (G samples/pass, G from ws_size).
// 8 logical samples: 0..3 = x, 4..7 = x1. Output flat: sample ns at ns*SAMP.
// R7: gemm_conv family converted to bf16x3 MFMA (mfma_f32_16x16x32_bf16):
//     A = W (k-contiguous), B staged transposed [p][k] bf16 hi/lo in LDS.
//     D = Ah*Bh + Ah*Bl + Al*Bh  (Al*Bl dropped, ~2^-18 rel) -> fp32-grade
//     accuracy at ~690 TF effective ceiling (vs 157 TF fp32 VALU).
//     All non-GEMM kernels are the R0 (3233us) versions verbatim.
//     R6 post-mortem: acc[8][16] fp32 tile spilled to scratch (WRITE_SIZE
//     31x amplified); fp32 VALU ~34% of peak is a dead end.
// Workspace per chunk-sample: A 3.84M f | Zs 2.56M f | aT 0.48M f | sp 15000
//   | as 1875 = 27,587,500 B per G. G adaptive in {8,4,2,1}.
// ---------------------------------------------------------------------------

#define PP 10000          // T*V
#define SAMP 2560000      // C*PP
#define BM 128
#define BN 128
#define BKc 8

typedef __attribute__((ext_vector_type(8))) __bf16 bf16x8;
typedef __attribute__((ext_vector_type(4))) float f32x4;

__device__ __forceinline__ float4 ld4(const float* p) { return *(const float4*)p; }
__device__ __forceinline__ float lrelu(float v) { return v >= 0.f ? v : 0.1f * v; }

// ---------------------------------------------------------------------------
// bf16x3 MFMA conv-as-GEMM. blockIdx.z = ln (chunk-local sample).
// MODE 0: out = acc + bias
// MODE 1: out = lrelu(res + g*(acc+bias) + beta)            (ff)
// MODE 2: out = acc                                         (out-gemm s=0)
// MODE 3: out += acc                                        (out-gemm s=1)
// MODE 4: out = lrelu(res + g*(out + acc + bias) + beta)    (out-gemm s=2)
// MODE 5: out = acc + bias, written as qkT[sec][t][v*64+cl] (temporal in-gemm)
// Tile: 128m x 128p x 32k. 4 waves (2x2), wave = 64x64 = 4x4 16x16 frags.
// A-frag: lane row=l&15, k=(l>>4)*8+i (k-contig).  B-frag: col=l&15, same k.
// C/D: col=l&15, row=(l>>4)*4+reg  [verified layout, learn_hip m89/m91].
// ---------------------------------------------------------------------------
template<int MODE, bool PE, bool BGLOB, bool OUTGLOB>
__global__ __launch_bounds__(256)
void gemm_mfma(const float* __restrict__ W, int Kw,
               const float* __restrict__ bias,
               const float* __restrict__ g, const float* __restrict__ beta,
               const float* __restrict__ bg0, const float* __restrict__ bg1,
               const float* __restrict__ bw,
               const float* __restrict__ pe,
               const float* rg0, const float* rg1,
               float* out, int n0, int M, int K)
{
    const int ln = blockIdx.z;
    const int ns = n0 + ln;
    const int p0 = blockIdx.x * 128;
    const int m0 = blockIdx.y * 128;
    const int tid = threadIdx.x;

    const float* Bp;
    if (BGLOB)
        Bp = (ns < 4) ? bg0 + (size_t)ns * (size_t)K * PP
                      : bg1 + (size_t)(ns - 4) * (size_t)K * PP;
    else
        Bp = bw + (size_t)ln * (size_t)K * PP;

    // pad to 56 shorts (112B row stride, 16B aligned, 8-clk-floor banking)
    __shared__ __align__(16) __bf16 Ah[128][56];
    __shared__ __align__(16) __bf16 Al[128][56];
    __shared__ __align__(16) __bf16 Bh[128][56];
    __shared__ __align__(16) __bf16 Bl[128][56];

    // staging roles
    const int am  = tid >> 1;            // A row 0..127
    const int akb = (tid & 1) * 16;      // A k base 0/16
    const float* wrow = W + (size_t)(m0 + am) * Kw + akb;

    const int bp  = tid & 127;           // B p 0..127
    const int bkg = (tid >> 7) * 8;      // B k base 0 or 8 (e adds 16)
    const int gp  = p0 + bp;
    const bool pok = gp < PP;

    // wave/frag roles
    const int lane = tid & 63;
    const int wv = tid >> 6;
    const int wr = (wv >> 1) * 64, wc = (wv & 1) * 64;
    const int lr = lane & 15;            // frag row (A: m, B: p)
    const int lk = (lane >> 4) * 8;      // frag k base

    f32x4 acc[4][4];
#pragma unroll
    for (int i = 0; i < 4; i++)
#pragma unroll
        for (int j = 0; j < 4; j++) acc[i][j] = (f32x4){0.f, 0.f, 0.f, 0.f};

    float4 wreg[4];
    float  breg[2][8];

    auto loadAB = [&](int kc) {
#pragma unroll
        for (int q = 0; q < 4; q++) wreg[q] = ld4(wrow + kc + q * 4);
#pragma unroll
        for (int e = 0; e < 2; e++) {
            const int kk = kc + bkg + e * 16;
#pragma unroll
            for (int i = 0; i < 8; i++) {
                float v = 0.f;
                if (pok) {
                    v = Bp[(size_t)(kk + i) * PP + gp];
                    if (PE) v += pe[(size_t)(kk + i) * PP + gp];
                }
                breg[e][i] = v;
            }
        }
    };

    loadAB(0);

    for (int k0 = 0; k0 < K; k0 += 32) {
        // convert staged regs -> bf16 hi/lo, write LDS
        {
            bf16x8 h0, h1, l0, l1;
#pragma unroll
            for (int q = 0; q < 4; q++) {
                const float vs0 = wreg[q].x, vs1 = wreg[q].y, vs2 = wreg[q].z, vs3 = wreg[q].w;
                __bf16 hh; const int ib = q * 4;
#define CVTA(c, val) { hh = (__bf16)(val); __bf16 ll = (__bf16)((val) - (float)hh); \
    if (ib + c < 8) { h0[ib + c] = hh; l0[ib + c] = ll; } else { h1[ib + c - 8] = hh; l1[ib + c - 8] = ll; } }
                CVTA(0, vs0) CVTA(1, vs1) CVTA(2, vs2) CVTA(3, vs3)
#undef CVTA
            }
            *(bf16x8*)&Ah[am][akb]     = h0;
            *(bf16x8*)&Ah[am][akb + 8] = h1;
            *(bf16x8*)&Al[am][akb]     = l0;
            *(bf16x8*)&Al[am][akb + 8] = l1;
        }
#pragma unroll
        for (int e = 0; e < 2; e++) {
            const int kk = bkg + e * 16;
            bf16x8 hb, lb;
#pragma unroll
            for (int i = 0; i < 8; i++) {
                __bf16 hh = (__bf16)breg[e][i];
                hb[i] = hh;
                lb[i] = (__bf16)(breg[e][i] - (float)hh);
            }
            *(bf16x8*)&Bh[bp][kk] = hb;
            *(bf16x8*)&Bl[bp][kk] = lb;
        }
        __syncthreads();

        const int kn = k0 + 32;
        if (kn < K) loadAB(kn);   // issue next chunk's loads under the MFMAs

        bf16x8 fbh[4], fbl[4];
#pragma unroll
        for (int fj = 0; fj < 4; fj++) {
            fbh[fj] = *(bf16x8*)&Bh[wc + fj * 16 + lr][lk];
            fbl[fj] = *(bf16x8*)&Bl[wc + fj * 16 + lr][lk];
        }
#pragma unroll
        for (int fi = 0; fi < 4; fi++) {
            bf16x8 fah = *(bf16x8*)&Ah[wr + fi * 16 + lr][lk];
            bf16x8 fal = *(bf16x8*)&Al[wr + fi * 16 + lr][lk];
#pragma unroll
            for (int fj = 0; fj < 4; fj++) {
                acc[fi][fj] = __builtin_amdgcn_mfma_f32_16x16x32_bf16(fah, fbh[fj], acc[fi][fj], 0, 0, 0);
                acc[fi][fj] = __builtin_amdgcn_mfma_f32_16x16x32_bf16(fah, fbl[fj], acc[fi][fj], 0, 0, 0);
                acc[fi][fj] = __builtin_amdgcn_mfma_f32_16x16x32_bf16(fal, fbh[fj], acc[fi][fj], 0, 0, 0);
            }
        }
        __syncthreads();
    }

    const int rb = (lane >> 4) * 4;      // frag row base (C/D layout)

    if (MODE == 5) {
        // Transposed write: qkT[ln][sec][t][v*64 + cl]; float4 over reg dim.
#pragma unroll
        for (int fi = 0; fi < 4; fi++) {
            const int mb = m0 + wr + fi * 16 + rb;
            const int sec = mb >> 6, cl = mb & 63;
            float* qt = out + (size_t)ln * 3840000ull + (size_t)sec * 640000ull + cl;
            const float b0 = bias[mb], b1 = bias[mb + 1], b2 = bias[mb + 2], b3 = bias[mb + 3];
#pragma unroll
            for (int fj = 0; fj < 4; fj++) {
                const int p = p0 + wc + fj * 16 + lr;
                if (p >= PP) continue;
                const int t = p / 25, v = p - t * 25;
                f32x4 a = acc[fi][fj];
                *(float4*)(qt + (size_t)t * 1600 + v * 64) =
                    make_float4(a[0] + b0, a[1] + b1, a[2] + b2, a[3] + b3);
            }
        }
        return;
    }

    float* op = out + (OUTGLOB ? (size_t)ns : (size_t)ln) * (size_t)M * PP;
    const float* resp = nullptr;
    if (MODE == 1 || MODE == 4)
        resp = (ns < 4) ? rg0 + (size_t)ns * SAMP : rg1 + (size_t)(ns - 4) * SAMP;

#pragma unroll
    for (int fi = 0; fi < 4; fi++) {
#pragma unroll
        for (int r = 0; r < 4; r++) {
            const int m = m0 + wr + fi * 16 + rb + r;
            const float bi = (MODE == 0 || MODE == 1 || MODE == 4) ? bias[m] : 0.f;
            const float gi = (MODE == 1 || MODE == 4) ? g[m] : 0.f;
            const float be = (MODE == 1 || MODE == 4) ? beta[m] : 0.f;
            const size_t rowoff = (size_t)m * PP;
#pragma unroll
            for (int fj = 0; fj < 4; fj++) {
                const int p = p0 + wc + fj * 16 + lr;
                if (p >= PP) continue;
                const float a = acc[fi][fj][r];
                float val;
                if (MODE == 0)      val = a + bi;
                else if (MODE == 2) val = a;
                else if (MODE == 3) val = op[rowoff + p] + a;
                else if (MODE == 4) val = lrelu(resp[rowoff + p] + gi * (op[rowoff + p] + a + bi) + be);
                else                val = lrelu(resp[rowoff + p] + gi * (a + bi) + be);
                op[rowoff + p] = val;
            }
        }
    }
}

// ---------------------------------------------------------------------------
// Spatial scores, partial K: 200 chunks of 128 rows. Grid (200, 3, G).  [R0]
// ---------------------------------------------------------------------------
__global__ __launch_bounds__(256)
void scores_s_partial(const float* __restrict__ qk, float* __restrict__ part)
{
    const int chunk = blockIdx.x, s = blockIdx.y, ln = blockIdx.z;
    const float* qsec = qk + ((size_t)ln * 384 + s * 64) * PP + (size_t)chunk * 3200;
    const float* ksec = qk + ((size_t)ln * 384 + (3 + s) * 64) * PP + (size_t)chunk * 3200;
    __shared__ float QL[3200];
    __shared__ float KL[3200];
    const int tid = threadIdx.x;
    for (int i = tid; i < 3200; i += 256) {
        QL[i] = qsec[i];
        KL[i] = ksec[i];
    }
    __syncthreads();
    const int o0 = tid, o1 = tid + 256, o2 = tid + 512;
    const int u0 = o0 / 25, v0 = o0 % 25;
    const int u1 = o1 / 25, v1 = o1 % 25;
    const int u2 = o2 / 25, v2 = o2 % 25;
    float a0 = 0.f, a1 = 0.f, a2 = 0.f;
#pragma unroll 8
    for (int r = 0; r < 128; r++) {
        int ro = r * 25;
        a0 = fmaf(QL[ro + u0], KL[ro + v0], a0);
        a1 = fmaf(QL[ro + u1], KL[ro + v1], a1);
        if (tid < 113) a2 = fmaf(QL[ro + u2], KL[ro + v2], a2);
    }
    float* pp = part + (((size_t)(ln * 3 + s)) * 200 + chunk) * 625;
    pp[o0] = a0;
    pp[o1] = a1;
    if (tid < 113) pp[o2] = a2;
}

// grid.x = 3*G blocks (idx = ln*3+s), 640 threads. Sums 200 partials.  [R0]
__global__ void scores_s_final(const float* __restrict__ part,
                               const float* __restrict__ alphas,
                               const float* __restrict__ att0s,
                               float* __restrict__ atts)
{
    const int idx = blockIdx.x;
    const int s = idx % 3;
    const int o = threadIdx.x;
    if (o >= 625) return;
    const float* pb = part + (size_t)idx * 200 * 625 + o;
    float sum = 0.f;
#pragma unroll 8
    for (int i = 0; i < 200; i++) sum += pb[(size_t)i * 625];
    atts[(size_t)idx * 625 + o] = tanhf(sum * (1.f / 25600.f)) * alphas[s] + att0s[s * 625 + o];
}

// ---------------------------------------------------------------------------
// Spatial apply (one s). Grid (200, G).  [R0]
// ---------------------------------------------------------------------------
__global__ __launch_bounds__(256)
void apply_s_kernel(const float* __restrict__ x0, const float* __restrict__ x1,
                    const float* __restrict__ atts, float* __restrict__ z,
                    int n0, int s)
{
    const int ln = blockIdx.y;
    const int ns = n0 + ln;
    const int tid = threadIdx.x;
    __shared__ float attL[700];   // 25*28 padded
    for (int i = tid; i < 700; i += 256) attL[i] = 0.f;
    __syncthreads();
    for (int i = tid; i < 625; i += 256) {
        int v = i / 25, w = i % 25;
        attL[v * 28 + w] = atts[(size_t)ln * 1875 + s * 625 + i];
    }
    __syncthreads();
    const float* xp = (ns < 4) ? x0 + (size_t)ns * SAMP : x1 + (size_t)(ns - 4) * SAMP;
    const int r0 = (blockIdx.x * 256 + tid) * 2;   // even; both rows share c
    const float* xr0 = xp + (size_t)r0 * 25;
    float xr[2][25];
#pragma unroll
    for (int i = 0; i < 2; i++)
#pragma unroll
        for (int v = 0; v < 25; v++) xr[i][v] = xr0[i * 25 + v];
    const int c0 = r0 / 400, t0 = r0 % 400;

    float4 acc0[7], acc1[7];
#pragma unroll
    for (int w4 = 0; w4 < 7; w4++) {
        acc0[w4] = make_float4(0.f, 0.f, 0.f, 0.f);
        acc1[w4] = make_float4(0.f, 0.f, 0.f, 0.f);
    }
#pragma unroll
    for (int v = 0; v < 25; v++) {
        const float4* arow = (const float4*)&attL[v * 28];
        float xv0 = xr[0][v], xv1 = xr[1][v];
#pragma unroll
        for (int w4 = 0; w4 < 7; w4++) {
            float4 a = arow[w4];
            acc0[w4].x = fmaf(xv0, a.x, acc0[w4].x);
            acc0[w4].y = fmaf(xv0, a.y, acc0[w4].y);
            acc0[w4].z = fmaf(xv0, a.z, acc0[w4].z);
            acc0[w4].w = fmaf(xv0, a.w, acc0[w4].w);
            acc1[w4].x = fmaf(xv1, a.x, acc1[w4].x);
            acc1[w4].y = fmaf(xv1, a.y, acc1[w4].y);
            acc1[w4].z = fmaf(xv1, a.z, acc1[w4].z);
            acc1[w4].w = fmaf(xv1, a.w, acc1[w4].w);
        }
    }
    float* zp = z + (size_t)ln * SAMP + (size_t)c0 * PP + (size_t)t0 * 25;
#pragma unroll
    for (int w4 = 0; w4 < 7; w4++) {
        int wb = w4 * 4;
        if (wb + 0 < 25) zp[wb + 0] = acc0[w4].x;
        if (wb + 1 < 25) zp[wb + 1] = acc0[w4].y;
        if (wb + 2 < 25) zp[wb + 2] = acc0[w4].z;
        if (wb + 3 < 25) zp[wb + 3] = acc0[w4].w;
    }
#pragma unroll
    for (int w4 = 0; w4 < 7; w4++) {
        int wb = w4 * 4;
        if (wb + 0 < 25) zp[25 + wb + 0] = acc1[w4].x;
        if (wb + 1 < 25) zp[25 + wb + 1] = acc1[w4].y;
        if (wb + 2 < 25) zp[25 + wb + 2] = acc1[w4].z;
        if (wb + 3 < 25) zp[25 + wb + 3] = acc1[w4].w;
    }
}

// ---------------------------------------------------------------------------
// Temporal scores GEMM. Grid (49, 2, 3*G).  [R0 single-buffer]
// ---------------------------------------------------------------------------
__global__ __launch_bounds__(256)
void scores_t_gemm(const float* __restrict__ qkT, float* __restrict__ part)
{
    const int idx = blockIdx.z;
    const int s = idx % 3, ln = idx / 3;
    const int ks = blockIdx.y;
    const int q0 = (blockIdx.x / 7) * 64, t0 = (blockIdx.x % 7) * 64;
    const float* base = qkT + (size_t)ln * 3840000ull;
    const float* Aq = base + (size_t)(3 + s) * 640000ull;   // rows = q
    const float* Bt = base + (size_t)s * 640000ull;         // rows = t
    __shared__ float As[8][68];
    __shared__ float Bs[8][68];
    const int tid = threadIdx.x, tx = tid & 15, ty = tid >> 4;
    float acc[4][4];
#pragma unroll
    for (int i = 0; i < 4; i++)
#pragma unroll
        for (int j = 0; j < 4; j++) acc[i][j] = 0.f;

    const int half = tid >> 7;          // 0 -> stage A, 1 -> stage B
    const int r = (tid & 127) >> 1;     // 0..63 tile row
    const int ak = (tid & 1) * 4;       // k offset 0/4
    const int row = (half ? t0 : q0) + r;
    const bool rok = row < 400;
    const float* srow = (half ? Bt : Aq) + (size_t)row * 1600 + ks * 800 + ak;
    float* dL = (half ? &Bs[0][0] : &As[0][0]) + ak * 68 + r;

    for (int k0 = 0; k0 < 800; k0 += 8) {
        float4 v = make_float4(0.f, 0.f, 0.f, 0.f);
        if (rok) v = ld4(srow + k0);
        __syncthreads();
        dL[0] = v.x; dL[68] = v.y; dL[136] = v.z; dL[204] = v.w;
        __syncthreads();
#pragma unroll
        for (int kk = 0; kk < 8; kk++) {
            float4 a = ld4(&As[kk][ty * 4]);
            float4 b = ld4(&Bs[kk][tx * 4]);
            float aR[4] = {a.x, a.y, a.z, a.w};
            float bR[4] = {b.x, b.y, b.z, b.w};
#pragma unroll
            for (int i = 0; i < 4; i++)
#pragma unroll
                for (int j = 0; j < 4; j++)
                    acc[i][j] = fmaf(aR[i], bR[j], acc[i][j]);
        }
    }

    float* pp_ = part + ((size_t)idx * 2 + ks) * 160000ull;
#pragma unroll
    for (int i = 0; i < 4; i++) {
        int q = q0 + ty * 4 + i;
        if (q >= 400) continue;
        int t = t0 + tx * 4;
        if (t + 3 < 400) {
            *(float4*)&pp_[(size_t)q * 400 + t] =
                make_float4(acc[i][0], acc[i][1], acc[i][2], acc[i][3]);
        } else {
#pragma unroll
            for (int j = 0; j < 4; j++)
                if (t + j < 400) pp_[(size_t)q * 400 + t + j] = acc[i][j];
        }
    }
}

// part0+part1 -> tanh -> aT[idx][q][t].  Grid (625, 3*G), 256 threads.  [R0]
__global__ void scores_t_final(const float* __restrict__ part,
                               const float* __restrict__ alphat,
                               const float* __restrict__ att0t,
                               float* __restrict__ aT)
{
    const int idx = blockIdx.y;
    const int s = idx % 3;
    const int o = blockIdx.x * 256 + threadIdx.x;   // q*400+t
    const int q = o / 400, t = o - q * 400;
    float sum = part[(size_t)(idx * 2) * 160000ull + o]
              + part[(size_t)(idx * 2 + 1) * 160000ull + o];
    aT[(size_t)idx * 160000ull + o] =
        tanhf(sum * (1.f / 1600.f)) * alphat[s] + att0t[((size_t)s * 400 + t) * 400 + q];
}

// ---------------------------------------------------------------------------
// Temporal apply (one s). Grid (50, 4, G).  [R0 version, VGPR 60, no dbuf]
// ---------------------------------------------------------------------------
__global__ __launch_bounds__(256)
void apply_t_kernel(const float* __restrict__ y, const float* __restrict__ attT,
                    float* __restrict__ z, int n0, int s)
{
    const int ln = blockIdx.z;
    const int ns = n0 + ln;
    const int j0 = blockIdx.x * 128;
    const int q0 = blockIdx.y * 128;
    const float* A = attT + ((size_t)ln * 3 + s) * 160000;
    const float* Y = y + (size_t)ns * SAMP;
    float* zout = z + (size_t)ln * SAMP;
    __shared__ float As[BKc][BM + 4];
    __shared__ float Bs[BKc][BN + 4];
    const int tid = threadIdx.x, tx = tid & 15, ty = tid >> 4;
    const int ar = tid >> 1, ak = (tid & 1) * 4;
    const int bk = tid >> 5;
    const int bj = (tid & 31) * 4;
    int bcc[4], bvv[4];
#pragma unroll
    for (int e = 0; e < 4; e++) { int j = j0 + bj + e; bcc[e] = j / 25; bvv[e] = j % 25; }
    float acc[8][8];
#pragma unroll
    for (int i = 0; i < 8; i++)
#pragma unroll
        for (int j = 0; j < 8; j++) acc[i][j] = 0.f;
    const int qA = q0 + ar;

    for (int k0 = 0; k0 < 400; k0 += BKc) {
        float4 av = make_float4(0.f, 0.f, 0.f, 0.f);
        if (qA < 400) av = ld4(&A[(size_t)qA * 400 + k0 + ak]);
        float bload[4];
#pragma unroll
        for (int e = 0; e < 4; e++)
            bload[e] = Y[(size_t)bcc[e] * PP + (size_t)(k0 + bk) * 25 + bvv[e]];
        __syncthreads();
        As[ak + 0][ar] = av.x;
        As[ak + 1][ar] = av.y;
        As[ak + 2][ar] = av.z;
        As[ak + 3][ar] = av.w;
        *(float4*)&Bs[bk][bj] = make_float4(bload[0], bload[1], bload[2], bload[3]);
        __syncthreads();
#pragma unroll
        for (int kk = 0; kk < BKc; kk++) {
            float4 a0 = ld4(&As[kk][ty * 8]);
            float4 a1 = ld4(&As[kk][ty * 8 + 4]);
            float4 b0 = ld4(&Bs[kk][tx * 4]);
            float4 b1 = ld4(&Bs[kk][64 + tx * 4]);
            float aR[8] = {a0.x, a0.y, a0.z, a0.w, a1.x, a1.y, a1.z, a1.w};
            float bR[8] = {b0.x, b0.y, b0.z, b0.w, b1.x, b1.y, b1.z, b1.w};
#pragma unroll
            for (int i = 0; i < 8; i++)
#pragma unroll
                for (int j = 0; j < 8; j++)
                    acc[i][j] = fmaf(aR[i], bR[j], acc[i][j]);
        }
    }

    int cS[8], vS[8];
#pragma unroll
    for (int jj = 0; jj < 4; jj++) {
        int j = j0 + tx * 4 + jj;       cS[jj] = j / 25;      vS[jj] = j % 25;
        int j2 = j0 + 64 + tx * 4 + jj; cS[4 + jj] = j2 / 25; vS[4 + jj] = j2 % 25;
    }
#pragma unroll
    for (int i = 0; i < 8; i++) {
        int q = q0 + ty * 8 + i;
        if (q >= 400) continue;
#pragma unroll
        for (int jj = 0; jj < 8; jj++)
            zout[(size_t)cS[jj] * PP + (size_t)q * 25 + vS[jj]] = acc[i][jj];
    }
}

// ---------------------------------------------------------------------------
extern "C" void kernel_launch(void* const* d_in, const int* in_sizes, int n_in,
                              void* d_out, int out_size, void* d_ws, size_t ws_size,
                              hipStream_t stream)
{
    const float* x    = (const float*)d_in[0];
    const float* x1   = (const float*)d_in[1];
    const float* pe_s = (const float*)d_in[2];
    const float* pe_t = (const float*)d_in[3];
    const float* Wsi  = (const float*)d_in[4];
    const float* bsi  = (const float*)d_in[5];
    const float* alphas = (const float*)d_in[6];
    const float* att0s  = (const float*)d_in[7];
    const float* Wso  = (const float*)d_in[8];
    const float* bso  = (const float*)d_in[9];
    const float* gso  = (const float*)d_in[10];
    const float* beso = (const float*)d_in[11];
    const float* Wsf  = (const float*)d_in[12];
    const float* bsf  = (const float*)d_in[13];
    const float* gsf  = (const float*)d_in[14];
    const float* besf = (const float*)d_in[15];
    const float* Wti  = (const float*)d_in[16];
    const float* bti  = (const float*)d_in[17];
    const float* alphat = (const float*)d_in[18];
    const float* att0t  = (const float*)d_in[19];
    const float* Wto  = (const float*)d_in[20];
    const float* bto  = (const float*)d_in[21];
    const float* gto  = (const float*)d_in[22];
    const float* beto = (const float*)d_in[23];
    const float* Wtf  = (const float*)d_in[24];
    const float* btf  = (const float*)d_in[25];
    const float* gtf  = (const float*)d_in[26];
    const float* betf = (const float*)d_in[27];

    float* outp = (float*)d_out;
    const float* outpB = outp + 4ull * SAMP;   // samples 4..7 view

    int G = 1;
    for (int g = 8; g >= 1; g >>= 1) {
        if ((size_t)g * 27587500ull <= ws_size) { G = g; break; }
    }

    float* A   = (float*)d_ws;                       // qk / qkT, then h overlay
    float* Zs  = A  + (size_t)G * 3840000ull;        // z slice / score partials
    float* aT  = Zs + (size_t)G * 2560000ull;        // temporal att
    float* sp  = aT + (size_t)G * 480000ull;         // (unused, kept for layout)
    float* as  = sp + (size_t)G * 15000ull;          // spatial att

    dim3 blk(256);
    for (int n0 = 0; n0 < 8; n0 += G) {
        dim3 gIn(79, 3, G), gOut(79, 2, G);

        // ---- spatial stage (input x / x1) ----
        gemm_mfma<0, true, true, false><<<gIn, blk, 0, stream>>>(
            Wsi, 256, bsi, nullptr, nullptr, x, x1, nullptr, pe_s,
            nullptr, nullptr, A, n0, 384, 256);
        scores_s_partial<<<dim3(200, 3, G), blk, 0, stream>>>(A, Zs);
        scores_s_final<<<dim3(3 * G), dim3(640), 0, stream>>>(Zs, alphas, att0s, as);
        for (int s = 0; s < 3; s++) {
            apply_s_kernel<<<dim3(200, G), blk, 0, stream>>>(x, x1, as, Zs, n0, s);
            if (s == 0)
                gemm_mfma<2, false, false, false><<<gOut, blk, 0, stream>>>(
                    Wso + s * 256, 768, nullptr, nullptr, nullptr, nullptr, nullptr, Zs,
                    nullptr, nullptr, nullptr, A, n0, 256, 256);
            else if (s == 1)
                gemm_mfma<3, false, false, false><<<gOut, blk, 0, stream>>>(
                    Wso + s * 256, 768, nullptr, nullptr, nullptr, nullptr, nullptr, Zs,
                    nullptr, nullptr, nullptr, A, n0, 256, 256);
            else
                gemm_mfma<4, false, false, false><<<gOut, blk, 0, stream>>>(
                    Wso + s * 256, 768, bso, gso, beso, nullptr, nullptr, Zs,
                    nullptr, x, x1, A, n0, 256, 256);
        }
        gemm_mfma<1, false, false, true><<<gOut, blk, 0, stream>>>(
            Wsf, 256, bsf, gsf, besf, nullptr, nullptr, A, nullptr,
            x, x1, outp, n0, 256, 256);

        // ---- temporal stage (input d_out, in place) ----
        gemm_mfma<5, true, true, false><<<gIn, blk, 0, stream>>>(
            Wti, 256, bti, nullptr, nullptr, outp, outpB, nullptr, pe_t,
            nullptr, nullptr, A, n0, 384, 256);
        scores_t_gemm<<<dim3(49, 2, 3 * G), blk, 0, stream>>>(A, Zs);
        scores_t_final<<<dim3(625, 3 * G), blk, 0, stream>>>(Zs, alphat, att0t, aT);
        for (int s = 0; s < 3; s++) {
            apply_t_kernel<<<dim3(50, 4, G), blk, 0, stream>>>(outp, aT, Zs, n0, s);
            if (s == 0)
                gemm_mfma<2, false, false, false><<<gOut, blk, 0, stream>>>(
                    Wto + s * 256, 768, nullptr, nullptr, nullptr, nullptr, nullptr, Zs,
                    nullptr, nullptr, nullptr, A, n0, 256, 256);
            else if (s == 1)
                gemm_mfma<3, false, false, false><<<gOut, blk, 0, stream>>>(
                    Wto + s * 256, 768, nullptr, nullptr, nullptr, nullptr, nullptr, Zs,
                    nullptr, nullptr, nullptr, A, n0, 256, 256);
            else
                gemm_mfma<4, false, false, false><<<gOut, blk, 0, stream>>>(
                    Wto + s * 256, 768, bto, gto, beto, nullptr, nullptr, Zs,
                    nullptr, outp, outpB, A, n0, 256, 256);
        }
        gemm_mfma<1, false, false, true><<<gOut, blk, 0, stream>>>(
            Wtf, 256, btf, gtf, betf, nullptr, nullptr, A, nullptr,
            outp, outpB, outp, n0, 256, 256);
    }
}

// Round 4
// 2284.313 us; speedup vs baseline: 3.3275x; 1.1720x over previous
//
#include <hip/hip_runtime.h>
#include <math.h>

// ---------------------------------------------------------------------------
// STAttentionRecBlock, sample-chunked (G samples/pass, G from ws_size).
// 8 logical samples: 0..3 = x, 4..7 = x1. Output flat: sample ns at ns*SAMP.
// R7: gemm_conv family -> bf16x3 MFMA (mfma_f32_16x16x32_bf16), 3233->2677us.
//     D = Ah*Bh + Ah*Bl + Al*Bh (Al*Bl dropped) -> fp32-grade accuracy at
//     ~690 TF effective ceiling. absmax unchanged vs fp32 (0.015625).
// R8: apply_t converted to the same bf16x3 MFMA structure (apply_t_mfma):
//     per (ln,s): z[q][j] = sum_t attT[q][t]*Y[j][t], M=400 N=6400 K=400.
//     A rows k-contig (like W); B staged transposed [j][k] (like Bp).
//     K zero-padded to 416; q guarded (4x128 tiles cover 400).
//     apply_t was 3x291us @ MfmaUtil 0 / VALUBusy 59% (fp32 VALU ceiling).
// Workspace per chunk-sample: A 3.84M f | Zs 2.56M f | aT 0.48M f | sp 15000
//   | as 1875 = 27,587,500 B per G. G adaptive in {8,4,2,1}.
// ---------------------------------------------------------------------------

#define PP 10000          // T*V
#define SAMP 2560000      // C*PP
#define BM 128
#define BN 128
#define BKc 8

typedef __attribute__((ext_vector_type(8))) __bf16 bf16x8;
typedef __attribute__((ext_vector_type(4))) float f32x4;

__device__ __forceinline__ float4 ld4(const float* p) { return *(const float4*)p; }
__device__ __forceinline__ float lrelu(float v) { return v >= 0.f ? v : 0.1f * v; }

// ---------------------------------------------------------------------------
// bf16x3 MFMA conv-as-GEMM. blockIdx.z = ln (chunk-local sample).
// MODE 0: out = acc + bias
// MODE 1: out = lrelu(res + g*(acc+bias) + beta)            (ff)
// MODE 2: out = acc                                         (out-gemm s=0)
// MODE 3: out += acc                                        (out-gemm s=1)
// MODE 4: out = lrelu(res + g*(out + acc + bias) + beta)    (out-gemm s=2)
// MODE 5: out = acc + bias, written as qkT[sec][t][v*64+cl] (temporal in-gemm)
// Tile: 128m x 128p x 32k. 4 waves (2x2), wave = 64x64 = 4x4 16x16 frags.
// ---------------------------------------------------------------------------
template<int MODE, bool PE, bool BGLOB, bool OUTGLOB>
__global__ __launch_bounds__(256)
void gemm_mfma(const float* __restrict__ W, int Kw,
               const float* __restrict__ bias,
               const float* __restrict__ g, const float* __restrict__ beta,
               const float* __restrict__ bg0, const float* __restrict__ bg1,
               const float* __restrict__ bw,
               const float* __restrict__ pe,
               const float* rg0, const float* rg1,
               float* out, int n0, int M, int K)
{
    const int ln = blockIdx.z;
    const int ns = n0 + ln;
    const int p0 = blockIdx.x * 128;
    const int m0 = blockIdx.y * 128;
    const int tid = threadIdx.x;

    const float* Bp;
    if (BGLOB)
        Bp = (ns < 4) ? bg0 + (size_t)ns * (size_t)K * PP
                      : bg1 + (size_t)(ns - 4) * (size_t)K * PP;
    else
        Bp = bw + (size_t)ln * (size_t)K * PP;

    // pad to 56 shorts (112B row stride, 16B aligned)
    __shared__ __align__(16) __bf16 Ah[128][56];
    __shared__ __align__(16) __bf16 Al[128][56];
    __shared__ __align__(16) __bf16 Bh[128][56];
    __shared__ __align__(16) __bf16 Bl[128][56];

    // staging roles
    const int am  = tid >> 1;            // A row 0..127
    const int akb = (tid & 1) * 16;      // A k base 0/16
    const float* wrow = W + (size_t)(m0 + am) * Kw + akb;

    const int bp  = tid & 127;           // B p 0..127
    const int bkg = (tid >> 7) * 8;      // B k base 0 or 8 (e adds 16)
    const int gp  = p0 + bp;
    const bool pok = gp < PP;

    // wave/frag roles
    const int lane = tid & 63;
    const int wv = tid >> 6;
    const int wr = (wv >> 1) * 64, wc = (wv & 1) * 64;
    const int lr = lane & 15;            // frag row (A: m, B: p)
    const int lk = (lane >> 4) * 8;      // frag k base

    f32x4 acc[4][4];
#pragma unroll
    for (int i = 0; i < 4; i++)
#pragma unroll
        for (int j = 0; j < 4; j++) acc[i][j] = (f32x4){0.f, 0.f, 0.f, 0.f};

    float4 wreg[4];
    float  breg[2][8];

    auto loadAB = [&](int kc) {
#pragma unroll
        for (int q = 0; q < 4; q++) wreg[q] = ld4(wrow + kc + q * 4);
#pragma unroll
        for (int e = 0; e < 2; e++) {
            const int kk = kc + bkg + e * 16;
#pragma unroll
            for (int i = 0; i < 8; i++) {
                float v = 0.f;
                if (pok) {
                    v = Bp[(size_t)(kk + i) * PP + gp];
                    if (PE) v += pe[(size_t)(kk + i) * PP + gp];
                }
                breg[e][i] = v;
            }
        }
    };

    loadAB(0);

    for (int k0 = 0; k0 < K; k0 += 32) {
        // convert staged regs -> bf16 hi/lo, write LDS
        {
            bf16x8 h0, h1, l0, l1;
#pragma unroll
            for (int q = 0; q < 4; q++) {
                const float vs0 = wreg[q].x, vs1 = wreg[q].y, vs2 = wreg[q].z, vs3 = wreg[q].w;
                __bf16 hh; const int ib = q * 4;
#define CVTA(c, val) { hh = (__bf16)(val); __bf16 ll = (__bf16)((val) - (float)hh); \
    if (ib + c < 8) { h0[ib + c] = hh; l0[ib + c] = ll; } else { h1[ib + c - 8] = hh; l1[ib + c - 8] = ll; } }
                CVTA(0, vs0) CVTA(1, vs1) CVTA(2, vs2) CVTA(3, vs3)
#undef CVTA
            }
            *(bf16x8*)&Ah[am][akb]     = h0;
            *(bf16x8*)&Ah[am][akb + 8] = h1;
            *(bf16x8*)&Al[am][akb]     = l0;
            *(bf16x8*)&Al[am][akb + 8] = l1;
        }
#pragma unroll
        for (int e = 0; e < 2; e++) {
            const int kk = bkg + e * 16;
            bf16x8 hb, lb;
#pragma unroll
            for (int i = 0; i < 8; i++) {
                __bf16 hh = (__bf16)breg[e][i];
                hb[i] = hh;
                lb[i] = (__bf16)(breg[e][i] - (float)hh);
            }
            *(bf16x8*)&Bh[bp][kk] = hb;
            *(bf16x8*)&Bl[bp][kk] = lb;
        }
        __syncthreads();

        const int kn = k0 + 32;
        if (kn < K) loadAB(kn);   // issue next chunk's loads under the MFMAs

        bf16x8 fbh[4], fbl[4];
#pragma unroll
        for (int fj = 0; fj < 4; fj++) {
            fbh[fj] = *(bf16x8*)&Bh[wc + fj * 16 + lr][lk];
            fbl[fj] = *(bf16x8*)&Bl[wc + fj * 16 + lr][lk];
        }
#pragma unroll
        for (int fi = 0; fi < 4; fi++) {
            bf16x8 fah = *(bf16x8*)&Ah[wr + fi * 16 + lr][lk];
            bf16x8 fal = *(bf16x8*)&Al[wr + fi * 16 + lr][lk];
#pragma unroll
            for (int fj = 0; fj < 4; fj++) {
                acc[fi][fj] = __builtin_amdgcn_mfma_f32_16x16x32_bf16(fah, fbh[fj], acc[fi][fj], 0, 0, 0);
                acc[fi][fj] = __builtin_amdgcn_mfma_f32_16x16x32_bf16(fah, fbl[fj], acc[fi][fj], 0, 0, 0);
                acc[fi][fj] = __builtin_amdgcn_mfma_f32_16x16x32_bf16(fal, fbh[fj], acc[fi][fj], 0, 0, 0);
            }
        }
        __syncthreads();
    }

    const int rb = (lane >> 4) * 4;      // frag row base (C/D layout)

    if (MODE == 5) {
        // Transposed write: qkT[ln][sec][t][v*64 + cl]; float4 over reg dim.
#pragma unroll
        for (int fi = 0; fi < 4; fi++) {
            const int mb = m0 + wr + fi * 16 + rb;
            const int sec = mb >> 6, cl = mb & 63;
            float* qt = out + (size_t)ln * 3840000ull + (size_t)sec * 640000ull + cl;
            const float b0 = bias[mb], b1 = bias[mb + 1], b2 = bias[mb + 2], b3 = bias[mb + 3];
#pragma unroll
            for (int fj = 0; fj < 4; fj++) {
                const int p = p0 + wc + fj * 16 + lr;
                if (p >= PP) continue;
                const int t = p / 25, v = p - t * 25;
                f32x4 a = acc[fi][fj];
                *(float4*)(qt + (size_t)t * 1600 + v * 64) =
                    make_float4(a[0] + b0, a[1] + b1, a[2] + b2, a[3] + b3);
            }
        }
        return;
    }

    float* op = out + (OUTGLOB ? (size_t)ns : (size_t)ln) * (size_t)M * PP;
    const float* resp = nullptr;
    if (MODE == 1 || MODE == 4)
        resp = (ns < 4) ? rg0 + (size_t)ns * SAMP : rg1 + (size_t)(ns - 4) * SAMP;

#pragma unroll
    for (int fi = 0; fi < 4; fi++) {
#pragma unroll
        for (int r = 0; r < 4; r++) {
            const int m = m0 + wr + fi * 16 + rb + r;
            const float bi = (MODE == 0 || MODE == 1 || MODE == 4) ? bias[m] : 0.f;
            const float gi = (MODE == 1 || MODE == 4) ? g[m] : 0.f;
            const float be = (MODE == 1 || MODE == 4) ? beta[m] : 0.f;
            const size_t rowoff = (size_t)m * PP;
#pragma unroll
            for (int fj = 0; fj < 4; fj++) {
                const int p = p0 + wc + fj * 16 + lr;
                if (p >= PP) continue;
                const float a = acc[fi][fj][r];
                float val;
                if (MODE == 0)      val = a + bi;
                else if (MODE == 2) val = a;
                else if (MODE == 3) val = op[rowoff + p] + a;
                else if (MODE == 4) val = lrelu(resp[rowoff + p] + gi * (op[rowoff + p] + a + bi) + be);
                else                val = lrelu(resp[rowoff + p] + gi * (a + bi) + be);
                op[rowoff + p] = val;
            }
        }
    }
}

// ---------------------------------------------------------------------------
// R8: temporal apply as bf16x3 MFMA. Grid (50, 4, G), one dispatch per s.
// z[ln][c][q][v] = sum_t attT[(ln*3+s)][q][t] * Y[ns][c][t][v]
// M=q (400, 4x128 tiles guarded), N=j=c*25+v (6400), K=t (400 -> pad 416).
// A = attT rows (k-contig); B = Y staged transposed [j][k] bf16 hi/lo.
// ---------------------------------------------------------------------------
__global__ __launch_bounds__(256)
void apply_t_mfma(const float* __restrict__ y, const float* __restrict__ attT,
                  float* __restrict__ z, int n0, int s)
{
    const int ln = blockIdx.z;
    const int ns = n0 + ln;
    const int j0 = blockIdx.x * 128;
    const int q0 = blockIdx.y * 128;
    const float* A = attT + ((size_t)ln * 3 + s) * 160000ull;
    const float* Y = y + (size_t)ns * SAMP;
    float* zout = z + (size_t)ln * SAMP;
    const int tid = threadIdx.x;

    __shared__ __align__(16) __bf16 Ah[128][56];
    __shared__ __align__(16) __bf16 Al[128][56];
    __shared__ __align__(16) __bf16 Bh[128][56];
    __shared__ __align__(16) __bf16 Bl[128][56];

    // A staging: row am (q), k base akb
    const int am  = tid >> 1;
    const int akb = (tid & 1) * 16;
    const int qA  = q0 + am;
    const float* arow = A + (size_t)qA * 400;

    // B staging: row bp (j), k group
    const int bp  = tid & 127;
    const int bkg = (tid >> 7) * 8;
    const int j   = j0 + bp;
    const int cB  = j / 25, vB = j % 25;
    const float* yrow = Y + (size_t)cB * PP + vB;   // + t*25

    // wave/frag roles
    const int lane = tid & 63;
    const int wv = tid >> 6;
    const int wr = (wv >> 1) * 64, wc = (wv & 1) * 64;
    const int lr = lane & 15;
    const int lk = (lane >> 4) * 8;

    f32x4 acc[4][4];
#pragma unroll
    for (int i = 0; i < 4; i++)
#pragma unroll
        for (int jj = 0; jj < 4; jj++) acc[i][jj] = (f32x4){0.f, 0.f, 0.f, 0.f};

    float4 wreg[4];
    float  breg[2][8];

    auto loadAB = [&](int kc) {
#pragma unroll
        for (int q = 0; q < 4; q++) {
            const int ks_ = kc + akb + q * 4;     // multiple of 4
            float4 v = make_float4(0.f, 0.f, 0.f, 0.f);
            if (qA < 400 && ks_ < 400) v = ld4(arow + ks_);
            wreg[q] = v;
        }
#pragma unroll
        for (int e = 0; e < 2; e++) {
            const int kb = kc + bkg + e * 16;
#pragma unroll
            for (int i = 0; i < 8; i++) {
                const int t = kb + i;
                breg[e][i] = (t < 400) ? yrow[(size_t)t * 25] : 0.f;
            }
        }
    };

    loadAB(0);

    for (int k0 = 0; k0 < 416; k0 += 32) {
        {
            bf16x8 h0, h1, l0, l1;
#pragma unroll
            for (int q = 0; q < 4; q++) {
                const float vs0 = wreg[q].x, vs1 = wreg[q].y, vs2 = wreg[q].z, vs3 = wreg[q].w;
                __bf16 hh; const int ib = q * 4;
#define CVTA(c, val) { hh = (__bf16)(val); __bf16 ll = (__bf16)((val) - (float)hh); \
    if (ib + c < 8) { h0[ib + c] = hh; l0[ib + c] = ll; } else { h1[ib + c - 8] = hh; l1[ib + c - 8] = ll; } }
                CVTA(0, vs0) CVTA(1, vs1) CVTA(2, vs2) CVTA(3, vs3)
#undef CVTA
            }
            *(bf16x8*)&Ah[am][akb]     = h0;
            *(bf16x8*)&Ah[am][akb + 8] = h1;
            *(bf16x8*)&Al[am][akb]     = l0;
            *(bf16x8*)&Al[am][akb + 8] = l1;
        }
#pragma unroll
        for (int e = 0; e < 2; e++) {
            const int kk = bkg + e * 16;
            bf16x8 hb, lb;
#pragma unroll
            for (int i = 0; i < 8; i++) {
                __bf16 hh = (__bf16)breg[e][i];
                hb[i] = hh;
                lb[i] = (__bf16)(breg[e][i] - (float)hh);
            }
            *(bf16x8*)&Bh[bp][kk] = hb;
            *(bf16x8*)&Bl[bp][kk] = lb;
        }
        __syncthreads();

        const int kn = k0 + 32;
        if (kn < 416) loadAB(kn);

        bf16x8 fbh[4], fbl[4];
#pragma unroll
        for (int fj = 0; fj < 4; fj++) {
            fbh[fj] = *(bf16x8*)&Bh[wc + fj * 16 + lr][lk];
            fbl[fj] = *(bf16x8*)&Bl[wc + fj * 16 + lr][lk];
        }
#pragma unroll
        for (int fi = 0; fi < 4; fi++) {
            bf16x8 fah = *(bf16x8*)&Ah[wr + fi * 16 + lr][lk];
            bf16x8 fal = *(bf16x8*)&Al[wr + fi * 16 + lr][lk];
#pragma unroll
            for (int fj = 0; fj < 4; fj++) {
                acc[fi][fj] = __builtin_amdgcn_mfma_f32_16x16x32_bf16(fah, fbh[fj], acc[fi][fj], 0, 0, 0);
                acc[fi][fj] = __builtin_amdgcn_mfma_f32_16x16x32_bf16(fah, fbl[fj], acc[fi][fj], 0, 0, 0);
                acc[fi][fj] = __builtin_amdgcn_mfma_f32_16x16x32_bf16(fal, fbh[fj], acc[fi][fj], 0, 0, 0);
            }
        }
        __syncthreads();
    }

    const int rb = (lane >> 4) * 4;
#pragma unroll
    for (int fi = 0; fi < 4; fi++) {
#pragma unroll
        for (int r = 0; r < 4; r++) {
            const int q = q0 + wr + fi * 16 + rb + r;
            if (q >= 400) continue;
#pragma unroll
            for (int fj = 0; fj < 4; fj++) {
                const int p = j0 + wc + fj * 16 + lr;
                const int c = p / 25, v = p - c * 25;
                zout[(size_t)c * PP + (size_t)q * 25 + v] = acc[fi][fj][r];
            }
        }
    }
}

// ---------------------------------------------------------------------------
// Spatial scores, partial K: 200 chunks of 128 rows. Grid (200, 3, G).  [R0]
// ---------------------------------------------------------------------------
__global__ __launch_bounds__(256)
void scores_s_partial(const float* __restrict__ qk, float* __restrict__ part)
{
    const int chunk = blockIdx.x, s = blockIdx.y, ln = blockIdx.z;
    const float* qsec = qk + ((size_t)ln * 384 + s * 64) * PP + (size_t)chunk * 3200;
    const float* ksec = qk + ((size_t)ln * 384 + (3 + s) * 64) * PP + (size_t)chunk * 3200;
    __shared__ float QL[3200];
    __shared__ float KL[3200];
    const int tid = threadIdx.x;
    for (int i = tid; i < 3200; i += 256) {
        QL[i] = qsec[i];
        KL[i] = ksec[i];
    }
    __syncthreads();
    const int o0 = tid, o1 = tid + 256, o2 = tid + 512;
    const int u0 = o0 / 25, v0 = o0 % 25;
    const int u1 = o1 / 25, v1 = o1 % 25;
    const int u2 = o2 / 25, v2 = o2 % 25;
    float a0 = 0.f, a1 = 0.f, a2 = 0.f;
#pragma unroll 8
    for (int r = 0; r < 128; r++) {
        int ro = r * 25;
        a0 = fmaf(QL[ro + u0], KL[ro + v0], a0);
        a1 = fmaf(QL[ro + u1], KL[ro + v1], a1);
        if (tid < 113) a2 = fmaf(QL[ro + u2], KL[ro + v2], a2);
    }
    float* pp = part + (((size_t)(ln * 3 + s)) * 200 + chunk) * 625;
    pp[o0] = a0;
    pp[o1] = a1;
    if (tid < 113) pp[o2] = a2;
}

// grid.x = 3*G blocks (idx = ln*3+s), 640 threads. Sums 200 partials.  [R0]
__global__ void scores_s_final(const float* __restrict__ part,
                               const float* __restrict__ alphas,
                               const float* __restrict__ att0s,
                               float* __restrict__ atts)
{
    const int idx = blockIdx.x;
    const int s = idx % 3;
    const int o = threadIdx.x;
    if (o >= 625) return;
    const float* pb = part + (size_t)idx * 200 * 625 + o;
    float sum = 0.f;
#pragma unroll 8
    for (int i = 0; i < 200; i++) sum += pb[(size_t)i * 625];
    atts[(size_t)idx * 625 + o] = tanhf(sum * (1.f / 25600.f)) * alphas[s] + att0s[s * 625 + o];
}

// ---------------------------------------------------------------------------
// Spatial apply (one s). Grid (200, G).  [R0]
// ---------------------------------------------------------------------------
__global__ __launch_bounds__(256)
void apply_s_kernel(const float* __restrict__ x0, const float* __restrict__ x1,
                    const float* __restrict__ atts, float* __restrict__ z,
                    int n0, int s)
{
    const int ln = blockIdx.y;
    const int ns = n0 + ln;
    const int tid = threadIdx.x;
    __shared__ float attL[700];   // 25*28 padded
    for (int i = tid; i < 700; i += 256) attL[i] = 0.f;
    __syncthreads();
    for (int i = tid; i < 625; i += 256) {
        int v = i / 25, w = i % 25;
        attL[v * 28 + w] = atts[(size_t)ln * 1875 + s * 625 + i];
    }
    __syncthreads();
    const float* xp = (ns < 4) ? x0 + (size_t)ns * SAMP : x1 + (size_t)(ns - 4) * SAMP;
    const int r0 = (blockIdx.x * 256 + tid) * 2;   // even; both rows share c
    const float* xr0 = xp + (size_t)r0 * 25;
    float xr[2][25];
#pragma unroll
    for (int i = 0; i < 2; i++)
#pragma unroll
        for (int v = 0; v < 25; v++) xr[i][v] = xr0[i * 25 + v];
    const int c0 = r0 / 400, t0 = r0 % 400;

    float4 acc0[7], acc1[7];
#pragma unroll
    for (int w4 = 0; w4 < 7; w4++) {
        acc0[w4] = make_float4(0.f, 0.f, 0.f, 0.f);
        acc1[w4] = make_float4(0.f, 0.f, 0.f, 0.f);
    }
#pragma unroll
    for (int v = 0; v < 25; v++) {
        const float4* arow = (const float4*)&attL[v * 28];
        float xv0 = xr[0][v], xv1 = xr[1][v];
#pragma unroll
        for (int w4 = 0; w4 < 7; w4++) {
            float4 a = arow[w4];
            acc0[w4].x = fmaf(xv0, a.x, acc0[w4].x);
            acc0[w4].y = fmaf(xv0, a.y, acc0[w4].y);
            acc0[w4].z = fmaf(xv0, a.z, acc0[w4].z);
            acc0[w4].w = fmaf(xv0, a.w, acc0[w4].w);
            acc1[w4].x = fmaf(xv1, a.x, acc1[w4].x);
            acc1[w4].y = fmaf(xv1, a.y, acc1[w4].y);
            acc1[w4].z = fmaf(xv1, a.z, acc1[w4].z);
            acc1[w4].w = fmaf(xv1, a.w, acc1[w4].w);
        }
    }
    float* zp = z + (size_t)ln * SAMP + (size_t)c0 * PP + (size_t)t0 * 25;
#pragma unroll
    for (int w4 = 0; w4 < 7; w4++) {
        int wb = w4 * 4;
        if (wb + 0 < 25) zp[wb + 0] = acc0[w4].x;
        if (wb + 1 < 25) zp[wb + 1] = acc0[w4].y;
        if (wb + 2 < 25) zp[wb + 2] = acc0[w4].z;
        if (wb + 3 < 25) zp[wb + 3] = acc0[w4].w;
    }
#pragma unroll
    for (int w4 = 0; w4 < 7; w4++) {
        int wb = w4 * 4;
        if (wb + 0 < 25) zp[25 + wb + 0] = acc1[w4].x;
        if (wb + 1 < 25) zp[25 + wb + 1] = acc1[w4].y;
        if (wb + 2 < 25) zp[25 + wb + 2] = acc1[w4].z;
        if (wb + 3 < 25) zp[25 + wb + 3] = acc1[w4].w;
    }
}

// ---------------------------------------------------------------------------
// Temporal scores GEMM. Grid (49, 2, 3*G).  [R0 single-buffer]
// ---------------------------------------------------------------------------
__global__ __launch_bounds__(256)
void scores_t_gemm(const float* __restrict__ qkT, float* __restrict__ part)
{
    const int idx = blockIdx.z;
    const int s = idx % 3, ln = idx / 3;
    const int ks = blockIdx.y;
    const int q0 = (blockIdx.x / 7) * 64, t0 = (blockIdx.x % 7) * 64;
    const float* base = qkT + (size_t)ln * 3840000ull;
    const float* Aq = base + (size_t)(3 + s) * 640000ull;   // rows = q
    const float* Bt = base + (size_t)s * 640000ull;         // rows = t
    __shared__ float As[8][68];
    __shared__ float Bs[8][68];
    const int tid = threadIdx.x, tx = tid & 15, ty = tid >> 4;
    float acc[4][4];
#pragma unroll
    for (int i = 0; i < 4; i++)
#pragma unroll
        for (int j = 0; j < 4; j++) acc[i][j] = 0.f;

    const int half = tid >> 7;          // 0 -> stage A, 1 -> stage B
    const int r = (tid & 127) >> 1;     // 0..63 tile row
    const int ak = (tid & 1) * 4;       // k offset 0/4
    const int row = (half ? t0 : q0) + r;
    const bool rok = row < 400;
    const float* srow = (half ? Bt : Aq) + (size_t)row * 1600 + ks * 800 + ak;
    float* dL = (half ? &Bs[0][0] : &As[0][0]) + ak * 68 + r;

    for (int k0 = 0; k0 < 800; k0 += 8) {
        float4 v = make_float4(0.f, 0.f, 0.f, 0.f);
        if (rok) v = ld4(srow + k0);
        __syncthreads();
        dL[0] = v.x; dL[68] = v.y; dL[136] = v.z; dL[204] = v.w;
        __syncthreads();
#pragma unroll
        for (int kk = 0; kk < 8; kk++) {
            float4 a = ld4(&As[kk][ty * 4]);
            float4 b = ld4(&Bs[kk][tx * 4]);
            float aR[4] = {a.x, a.y, a.z, a.w};
            float bR[4] = {b.x, b.y, b.z, b.w};
#pragma unroll
            for (int i = 0; i < 4; i++)
#pragma unroll
                for (int j = 0; j < 4; j++)
                    acc[i][j] = fmaf(aR[i], bR[j], acc[i][j]);
        }
    }

    float* pp_ = part + ((size_t)idx * 2 + ks) * 160000ull;
#pragma unroll
    for (int i = 0; i < 4; i++) {
        int q = q0 + ty * 4 + i;
        if (q >= 400) continue;
        int t = t0 + tx * 4;
        if (t + 3 < 400) {
            *(float4*)&pp_[(size_t)q * 400 + t] =
                make_float4(acc[i][0], acc[i][1], acc[i][2], acc[i][3]);
        } else {
#pragma unroll
            for (int j = 0; j < 4; j++)
                if (t + j < 400) pp_[(size_t)q * 400 + t + j] = acc[i][j];
        }
    }
}

// part0+part1 -> tanh -> aT[idx][q][t].  Grid (625, 3*G), 256 threads.  [R0]
__global__ void scores_t_final(const float* __restrict__ part,
                               const float* __restrict__ alphat,
                               const float* __restrict__ att0t,
                               float* __restrict__ aT)
{
    const int idx = blockIdx.y;
    const int s = idx % 3;
    const int o = blockIdx.x * 256 + threadIdx.x;   // q*400+t
    const int q = o / 400, t = o - q * 400;
    float sum = part[(size_t)(idx * 2) * 160000ull + o]
              + part[(size_t)(idx * 2 + 1) * 160000ull + o];
    aT[(size_t)idx * 160000ull + o] =
        tanhf(sum * (1.f / 1600.f)) * alphat[s] + att0t[((size_t)s * 400 + t) * 400 + q];
}

// ---------------------------------------------------------------------------
extern "C" void kernel_launch(void* const* d_in, const int* in_sizes, int n_in,
                              void* d_out, int out_size, void* d_ws, size_t ws_size,
                              hipStream_t stream)
{
    const float* x    = (const float*)d_in[0];
    const float* x1   = (const float*)d_in[1];
    const float* pe_s = (const float*)d_in[2];
    const float* pe_t = (const float*)d_in[3];
    const float* Wsi  = (const float*)d_in[4];
    const float* bsi  = (const float*)d_in[5];
    const float* alphas = (const float*)d_in[6];
    const float* att0s  = (const float*)d_in[7];
    const float* Wso  = (const float*)d_in[8];
    const float* bso  = (const float*)d_in[9];
    const float* gso  = (const float*)d_in[10];
    const float* beso = (const float*)d_in[11];
    const float* Wsf  = (const float*)d_in[12];
    const float* bsf  = (const float*)d_in[13];
    const float* gsf  = (const float*)d_in[14];
    const float* besf = (const float*)d_in[15];
    const float* Wti  = (const float*)d_in[16];
    const float* bti  = (const float*)d_in[17];
    const float* alphat = (const float*)d_in[18];
    const float* att0t  = (const float*)d_in[19];
    const float* Wto  = (const float*)d_in[20];
    const float* bto  = (const float*)d_in[21];
    const float* gto  = (const float*)d_in[22];
    const float* beto = (const float*)d_in[23];
    const float* Wtf  = (const float*)d_in[24];
    const float* btf  = (const float*)d_in[25];
    const float* gtf  = (const float*)d_in[26];
    const float* betf = (const float*)d_in[27];

    float* outp = (float*)d_out;
    const float* outpB = outp + 4ull * SAMP;   // samples 4..7 view

    int G = 1;
    for (int g = 8; g >= 1; g >>= 1) {
        if ((size_t)g * 27587500ull <= ws_size) { G = g; break; }
    }

    float* A   = (float*)d_ws;                       // qk / qkT, then h overlay
    float* Zs  = A  + (size_t)G * 3840000ull;        // z slice / score partials
    float* aT  = Zs + (size_t)G * 2560000ull;        // temporal att
    float* sp  = aT + (size_t)G * 480000ull;         // (unused, kept for layout)
    float* as  = sp + (size_t)G * 15000ull;          // spatial att

    dim3 blk(256);
    for (int n0 = 0; n0 < 8; n0 += G) {
        dim3 gIn(79, 3, G), gOut(79, 2, G);

        // ---- spatial stage (input x / x1) ----
        gemm_mfma<0, true, true, false><<<gIn, blk, 0, stream>>>(
            Wsi, 256, bsi, nullptr, nullptr, x, x1, nullptr, pe_s,
            nullptr, nullptr, A, n0, 384, 256);
        scores_s_partial<<<dim3(200, 3, G), blk, 0, stream>>>(A, Zs);
        scores_s_final<<<dim3(3 * G), dim3(640), 0, stream>>>(Zs, alphas, att0s, as);
        for (int s = 0; s < 3; s++) {
            apply_s_kernel<<<dim3(200, G), blk, 0, stream>>>(x, x1, as, Zs, n0, s);
            if (s == 0)
                gemm_mfma<2, false, false, false><<<gOut, blk, 0, stream>>>(
                    Wso + s * 256, 768, nullptr, nullptr, nullptr, nullptr, nullptr, Zs,
                    nullptr, nullptr, nullptr, A, n0, 256, 256);
            else if (s == 1)
                gemm_mfma<3, false, false, false><<<gOut, blk, 0, stream>>>(
                    Wso + s * 256, 768, nullptr, nullptr, nullptr, nullptr, nullptr, Zs,
                    nullptr, nullptr, nullptr, A, n0, 256, 256);
            else
                gemm_mfma<4, false, false, false><<<gOut, blk, 0, stream>>>(
                    Wso + s * 256, 768, bso, gso, beso, nullptr, nullptr, Zs,
                    nullptr, x, x1, A, n0, 256, 256);
        }
        gemm_mfma<1, false, false, true><<<gOut, blk, 0, stream>>>(
            Wsf, 256, bsf, gsf, besf, nullptr, nullptr, A, nullptr,
            x, x1, outp, n0, 256, 256);

        // ---- temporal stage (input d_out, in place) ----
        gemm_mfma<5, true, true, false><<<gIn, blk, 0, stream>>>(
            Wti, 256, bti, nullptr, nullptr, outp, outpB, nullptr, pe_t,
            nullptr, nullptr, A, n0, 384, 256);
        scores_t_gemm<<<dim3(49, 2, 3 * G), blk, 0, stream>>>(A, Zs);
        scores_t_final<<<dim3(625, 3 * G), blk, 0, stream>>>(Zs, alphat, att0t, aT);
        for (int s = 0; s < 3; s++) {
            apply_t_mfma<<<dim3(50, 4, G), blk, 0, stream>>>(outp, aT, Zs, n0, s);
            if (s == 0)
                gemm_mfma<2, false, false, false><<<gOut, blk, 0, stream>>>(
                    Wto + s * 256, 768, nullptr, nullptr, nullptr, nullptr, nullptr, Zs,
                    nullptr, nullptr, nullptr, A, n0, 256, 256);
            else if (s == 1)
                gemm_mfma<3, false, false, false><<<gOut, blk, 0, stream>>>(
                    Wto + s * 256, 768, nullptr, nullptr, nullptr, nullptr, nullptr, Zs,
                    nullptr, nullptr, nullptr, A, n0, 256, 256);
            else
                gemm_mfma<4, false, false, false><<<gOut, blk, 0, stream>>>(
                    Wto + s * 256, 768, bto, gto, beto, nullptr, nullptr, Zs,
                    nullptr, outp, outpB, A, n0, 256, 256);
        }
        gemm_mfma<1, false, false, true><<<gOut, blk, 0, stream>>>(
            Wtf, 256, btf, gtf, betf, nullptr, nullptr, A, nullptr,
            outp, outpB, outp, n0, 256, 256);
    }
}

// Round 5
// 2031.107 us; speedup vs baseline: 3.7423x; 1.1247x over previous
//
#include <hip/hip_runtime.h>
#include <math.h>

// ---------------------------------------------------------------------------
// STAttentionRecBlock, sample-chunked (G samples/pass, G from ws_size).
// 8 logical samples: 0..3 = x, 4..7 = x1. Output flat: sample ns at ns*SAMP.
// R7: gemm_conv family -> bf16x3 MFMA, 3233->2677us.
// R8: apply_t -> bf16x3 MFMA (apply_t_mfma), 2677->2284us.
// R9: scores_t -> bf16x3 MFMA (scores_t_mfma) with fused tanh finalize:
//     att[q][t] = tanh(sum_k Aq[q][k]*Bt[t][k] / 1600)*alphat + att0t[t][q].
//     Both operands k-contiguous in qkT (no transpose staging); K=1600=50x32.
//     scores_t_final + part round-trip eliminated. Was 250us @ MfmaUtil 0,
//     VALUBusy 53%, HBM 31% (fp32 VALU wall).
// Workspace per chunk-sample: A 3.84M f | Zs 2.56M f | aT 0.48M f | sp 15000
//   | as 1875 = 27,587,500 B per G. G adaptive in {8,4,2,1}.
// ---------------------------------------------------------------------------

#define PP 10000          // T*V
#define SAMP 2560000      // C*PP

typedef __attribute__((ext_vector_type(8))) __bf16 bf16x8;
typedef __attribute__((ext_vector_type(4))) float f32x4;

__device__ __forceinline__ float4 ld4(const float* p) { return *(const float4*)p; }
__device__ __forceinline__ float lrelu(float v) { return v >= 0.f ? v : 0.1f * v; }

// ---------------------------------------------------------------------------
// bf16x3 MFMA conv-as-GEMM. blockIdx.z = ln (chunk-local sample).
// MODE 0: out = acc + bias
// MODE 1: out = lrelu(res + g*(acc+bias) + beta)            (ff)
// MODE 2: out = acc                                         (out-gemm s=0)
// MODE 3: out += acc                                        (out-gemm s=1)
// MODE 4: out = lrelu(res + g*(out + acc + bias) + beta)    (out-gemm s=2)
// MODE 5: out = acc + bias, written as qkT[sec][t][v*64+cl] (temporal in-gemm)
// Tile: 128m x 128p x 32k. 4 waves (2x2), wave = 64x64 = 4x4 16x16 frags.
// ---------------------------------------------------------------------------
template<int MODE, bool PE, bool BGLOB, bool OUTGLOB>
__global__ __launch_bounds__(256)
void gemm_mfma(const float* __restrict__ W, int Kw,
               const float* __restrict__ bias,
               const float* __restrict__ g, const float* __restrict__ beta,
               const float* __restrict__ bg0, const float* __restrict__ bg1,
               const float* __restrict__ bw,
               const float* __restrict__ pe,
               const float* rg0, const float* rg1,
               float* out, int n0, int M, int K)
{
    const int ln = blockIdx.z;
    const int ns = n0 + ln;
    const int p0 = blockIdx.x * 128;
    const int m0 = blockIdx.y * 128;
    const int tid = threadIdx.x;

    const float* Bp;
    if (BGLOB)
        Bp = (ns < 4) ? bg0 + (size_t)ns * (size_t)K * PP
                      : bg1 + (size_t)(ns - 4) * (size_t)K * PP;
    else
        Bp = bw + (size_t)ln * (size_t)K * PP;

    __shared__ __align__(16) __bf16 Ah[128][56];
    __shared__ __align__(16) __bf16 Al[128][56];
    __shared__ __align__(16) __bf16 Bh[128][56];
    __shared__ __align__(16) __bf16 Bl[128][56];

    const int am  = tid >> 1;            // A row 0..127
    const int akb = (tid & 1) * 16;      // A k base 0/16
    const float* wrow = W + (size_t)(m0 + am) * Kw + akb;

    const int bp  = tid & 127;           // B p 0..127
    const int bkg = (tid >> 7) * 8;      // B k base 0 or 8 (e adds 16)
    const int gp  = p0 + bp;
    const bool pok = gp < PP;

    const int lane = tid & 63;
    const int wv = tid >> 6;
    const int wr = (wv >> 1) * 64, wc = (wv & 1) * 64;
    const int lr = lane & 15;            // frag row (A: m, B: p)
    const int lk = (lane >> 4) * 8;      // frag k base

    f32x4 acc[4][4];
#pragma unroll
    for (int i = 0; i < 4; i++)
#pragma unroll
        for (int j = 0; j < 4; j++) acc[i][j] = (f32x4){0.f, 0.f, 0.f, 0.f};

    float4 wreg[4];
    float  breg[2][8];

    auto loadAB = [&](int kc) {
#pragma unroll
        for (int q = 0; q < 4; q++) wreg[q] = ld4(wrow + kc + q * 4);
#pragma unroll
        for (int e = 0; e < 2; e++) {
            const int kk = kc + bkg + e * 16;
#pragma unroll
            for (int i = 0; i < 8; i++) {
                float v = 0.f;
                if (pok) {
                    v = Bp[(size_t)(kk + i) * PP + gp];
                    if (PE) v += pe[(size_t)(kk + i) * PP + gp];
                }
                breg[e][i] = v;
            }
        }
    };

    loadAB(0);

    for (int k0 = 0; k0 < K; k0 += 32) {
        {
            bf16x8 h0, h1, l0, l1;
#pragma unroll
            for (int q = 0; q < 4; q++) {
                const float vs0 = wreg[q].x, vs1 = wreg[q].y, vs2 = wreg[q].z, vs3 = wreg[q].w;
                __bf16 hh; const int ib = q * 4;
#define CVTA(c, val) { hh = (__bf16)(val); __bf16 ll = (__bf16)((val) - (float)hh); \
    if (ib + c < 8) { h0[ib + c] = hh; l0[ib + c] = ll; } else { h1[ib + c - 8] = hh; l1[ib + c - 8] = ll; } }
                CVTA(0, vs0) CVTA(1, vs1) CVTA(2, vs2) CVTA(3, vs3)
#undef CVTA
            }
            *(bf16x8*)&Ah[am][akb]     = h0;
            *(bf16x8*)&Ah[am][akb + 8] = h1;
            *(bf16x8*)&Al[am][akb]     = l0;
            *(bf16x8*)&Al[am][akb + 8] = l1;
        }
#pragma unroll
        for (int e = 0; e < 2; e++) {
            const int kk = bkg + e * 16;
            bf16x8 hb, lb;
#pragma unroll
            for (int i = 0; i < 8; i++) {
                __bf16 hh = (__bf16)breg[e][i];
                hb[i] = hh;
                lb[i] = (__bf16)(breg[e][i] - (float)hh);
            }
            *(bf16x8*)&Bh[bp][kk] = hb;
            *(bf16x8*)&Bl[bp][kk] = lb;
        }
        __syncthreads();

        const int kn = k0 + 32;
        if (kn < K) loadAB(kn);   // issue next chunk's loads under the MFMAs

        bf16x8 fbh[4], fbl[4];
#pragma unroll
        for (int fj = 0; fj < 4; fj++) {
            fbh[fj] = *(bf16x8*)&Bh[wc + fj * 16 + lr][lk];
            fbl[fj] = *(bf16x8*)&Bl[wc + fj * 16 + lr][lk];
        }
#pragma unroll
        for (int fi = 0; fi < 4; fi++) {
            bf16x8 fah = *(bf16x8*)&Ah[wr + fi * 16 + lr][lk];
            bf16x8 fal = *(bf16x8*)&Al[wr + fi * 16 + lr][lk];
#pragma unroll
            for (int fj = 0; fj < 4; fj++) {
                acc[fi][fj] = __builtin_amdgcn_mfma_f32_16x16x32_bf16(fah, fbh[fj], acc[fi][fj], 0, 0, 0);
                acc[fi][fj] = __builtin_amdgcn_mfma_f32_16x16x32_bf16(fah, fbl[fj], acc[fi][fj], 0, 0, 0);
                acc[fi][fj] = __builtin_amdgcn_mfma_f32_16x16x32_bf16(fal, fbh[fj], acc[fi][fj], 0, 0, 0);
            }
        }
        __syncthreads();
    }

    const int rb = (lane >> 4) * 4;      // frag row base (C/D layout)

    if (MODE == 5) {
        // Transposed write: qkT[ln][sec][t][v*64 + cl]; float4 over reg dim.
#pragma unroll
        for (int fi = 0; fi < 4; fi++) {
            const int mb = m0 + wr + fi * 16 + rb;
            const int sec = mb >> 6, cl = mb & 63;
            float* qt = out + (size_t)ln * 3840000ull + (size_t)sec * 640000ull + cl;
            const float b0 = bias[mb], b1 = bias[mb + 1], b2 = bias[mb + 2], b3 = bias[mb + 3];
#pragma unroll
            for (int fj = 0; fj < 4; fj++) {
                const int p = p0 + wc + fj * 16 + lr;
                if (p >= PP) continue;
                const int t = p / 25, v = p - t * 25;
                f32x4 a = acc[fi][fj];
                *(float4*)(qt + (size_t)t * 1600 + v * 64) =
                    make_float4(a[0] + b0, a[1] + b1, a[2] + b2, a[3] + b3);
            }
        }
        return;
    }

    float* op = out + (OUTGLOB ? (size_t)ns : (size_t)ln) * (size_t)M * PP;
    const float* resp = nullptr;
    if (MODE == 1 || MODE == 4)
        resp = (ns < 4) ? rg0 + (size_t)ns * SAMP : rg1 + (size_t)(ns - 4) * SAMP;

#pragma unroll
    for (int fi = 0; fi < 4; fi++) {
#pragma unroll
        for (int r = 0; r < 4; r++) {
            const int m = m0 + wr + fi * 16 + rb + r;
            const float bi = (MODE == 0 || MODE == 1 || MODE == 4) ? bias[m] : 0.f;
            const float gi = (MODE == 1 || MODE == 4) ? g[m] : 0.f;
            const float be = (MODE == 1 || MODE == 4) ? beta[m] : 0.f;
            const size_t rowoff = (size_t)m * PP;
#pragma unroll
            for (int fj = 0; fj < 4; fj++) {
                const int p = p0 + wc + fj * 16 + lr;
                if (p >= PP) continue;
                const float a = acc[fi][fj][r];
                float val;
                if (MODE == 0)      val = a + bi;
                else if (MODE == 2) val = a;
                else if (MODE == 3) val = op[rowoff + p] + a;
                else if (MODE == 4) val = lrelu(resp[rowoff + p] + gi * (op[rowoff + p] + a + bi) + be);
                else                val = lrelu(resp[rowoff + p] + gi * (a + bi) + be);
                op[rowoff + p] = val;
            }
        }
    }
}

// ---------------------------------------------------------------------------
// R8: temporal apply as bf16x3 MFMA. Grid (50, 4, G), one dispatch per s.
// z[ln][c][q][v] = sum_t attT[(ln*3+s)][q][t] * Y[ns][c][t][v]
// ---------------------------------------------------------------------------
__global__ __launch_bounds__(256)
void apply_t_mfma(const float* __restrict__ y, const float* __restrict__ attT,
                  float* __restrict__ z, int n0, int s)
{
    const int ln = blockIdx.z;
    const int ns = n0 + ln;
    const int j0 = blockIdx.x * 128;
    const int q0 = blockIdx.y * 128;
    const float* A = attT + ((size_t)ln * 3 + s) * 160000ull;
    const float* Y = y + (size_t)ns * SAMP;
    float* zout = z + (size_t)ln * SAMP;
    const int tid = threadIdx.x;

    __shared__ __align__(16) __bf16 Ah[128][56];
    __shared__ __align__(16) __bf16 Al[128][56];
    __shared__ __align__(16) __bf16 Bh[128][56];
    __shared__ __align__(16) __bf16 Bl[128][56];

    const int am  = tid >> 1;
    const int akb = (tid & 1) * 16;
    const int qA  = q0 + am;
    const float* arow = A + (size_t)qA * 400;

    const int bp  = tid & 127;
    const int bkg = (tid >> 7) * 8;
    const int j   = j0 + bp;
    const int cB  = j / 25, vB = j % 25;
    const float* yrow = Y + (size_t)cB * PP + vB;   // + t*25

    const int lane = tid & 63;
    const int wv = tid >> 6;
    const int wr = (wv >> 1) * 64, wc = (wv & 1) * 64;
    const int lr = lane & 15;
    const int lk = (lane >> 4) * 8;

    f32x4 acc[4][4];
#pragma unroll
    for (int i = 0; i < 4; i++)
#pragma unroll
        for (int jj = 0; jj < 4; jj++) acc[i][jj] = (f32x4){0.f, 0.f, 0.f, 0.f};

    float4 wreg[4];
    float  breg[2][8];

    auto loadAB = [&](int kc) {
#pragma unroll
        for (int q = 0; q < 4; q++) {
            const int ks_ = kc + akb + q * 4;
            float4 v = make_float4(0.f, 0.f, 0.f, 0.f);
            if (qA < 400 && ks_ < 400) v = ld4(arow + ks_);
            wreg[q] = v;
        }
#pragma unroll
        for (int e = 0; e < 2; e++) {
            const int kb = kc + bkg + e * 16;
#pragma unroll
            for (int i = 0; i < 8; i++) {
                const int t = kb + i;
                breg[e][i] = (t < 400) ? yrow[(size_t)t * 25] : 0.f;
            }
        }
    };

    loadAB(0);

    for (int k0 = 0; k0 < 416; k0 += 32) {
        {
            bf16x8 h0, h1, l0, l1;
#pragma unroll
            for (int q = 0; q < 4; q++) {
                const float vs0 = wreg[q].x, vs1 = wreg[q].y, vs2 = wreg[q].z, vs3 = wreg[q].w;
                __bf16 hh; const int ib = q * 4;
#define CVTA(c, val) { hh = (__bf16)(val); __bf16 ll = (__bf16)((val) - (float)hh); \
    if (ib + c < 8) { h0[ib + c] = hh; l0[ib + c] = ll; } else { h1[ib + c - 8] = hh; l1[ib + c - 8] = ll; } }
                CVTA(0, vs0) CVTA(1, vs1) CVTA(2, vs2) CVTA(3, vs3)
#undef CVTA
            }
            *(bf16x8*)&Ah[am][akb]     = h0;
            *(bf16x8*)&Ah[am][akb + 8] = h1;
            *(bf16x8*)&Al[am][akb]     = l0;
            *(bf16x8*)&Al[am][akb + 8] = l1;
        }
#pragma unroll
        for (int e = 0; e < 2; e++) {
            const int kk = bkg + e * 16;
            bf16x8 hb, lb;
#pragma unroll
            for (int i = 0; i < 8; i++) {
                __bf16 hh = (__bf16)breg[e][i];
                hb[i] = hh;
                lb[i] = (__bf16)(breg[e][i] - (float)hh);
            }
            *(bf16x8*)&Bh[bp][kk] = hb;
            *(bf16x8*)&Bl[bp][kk] = lb;
        }
        __syncthreads();

        const int kn = k0 + 32;
        if (kn < 416) loadAB(kn);

        bf16x8 fbh[4], fbl[4];
#pragma unroll
        for (int fj = 0; fj < 4; fj++) {
            fbh[fj] = *(bf16x8*)&Bh[wc + fj * 16 + lr][lk];
            fbl[fj] = *(bf16x8*)&Bl[wc + fj * 16 + lr][lk];
        }
#pragma unroll
        for (int fi = 0; fi < 4; fi++) {
            bf16x8 fah = *(bf16x8*)&Ah[wr + fi * 16 + lr][lk];
            bf16x8 fal = *(bf16x8*)&Al[wr + fi * 16 + lr][lk];
#pragma unroll
            for (int fj = 0; fj < 4; fj++) {
                acc[fi][fj] = __builtin_amdgcn_mfma_f32_16x16x32_bf16(fah, fbh[fj], acc[fi][fj], 0, 0, 0);
                acc[fi][fj] = __builtin_amdgcn_mfma_f32_16x16x32_bf16(fah, fbl[fj], acc[fi][fj], 0, 0, 0);
                acc[fi][fj] = __builtin_amdgcn_mfma_f32_16x16x32_bf16(fal, fbh[fj], acc[fi][fj], 0, 0, 0);
            }
        }
        __syncthreads();
    }

    const int rb = (lane >> 4) * 4;
#pragma unroll
    for (int fi = 0; fi < 4; fi++) {
#pragma unroll
        for (int r = 0; r < 4; r++) {
            const int q = q0 + wr + fi * 16 + rb + r;
            if (q >= 400) continue;
#pragma unroll
            for (int fj = 0; fj < 4; fj++) {
                const int p = j0 + wc + fj * 16 + lr;
                const int c = p / 25, v = p - c * 25;
                zout[(size_t)c * PP + (size_t)q * 25 + v] = acc[fi][fj][r];
            }
        }
    }
}

// ---------------------------------------------------------------------------
// R9: temporal scores as bf16x3 MFMA with fused finalize.
// aT[idx][q][t] = tanh(sum_k Aq[q][k]*Bt[t][k] / 1600)*alphat[s] + att0t[s][t][q]
// Aq = qkT[ln][3+s] (rows q, k-contig 1600), Bt = qkT[ln][s] (rows t).
// Grid (16, 3*G): blockIdx.x = qtile*4 + ttile; M/N guarded at 400.
// ---------------------------------------------------------------------------
__global__ __launch_bounds__(256)
void scores_t_mfma(const float* __restrict__ qkT,
                   const float* __restrict__ alphat,
                   const float* __restrict__ att0t,
                   float* __restrict__ aT)
{
    const int idx = blockIdx.y;          // ln*3 + s
    const int s = idx % 3, ln = idx / 3;
    const int t0 = (blockIdx.x & 3) * 128;
    const int q0 = (blockIdx.x >> 2) * 128;
    const float* base = qkT + (size_t)ln * 3840000ull;
    const float* Aq = base + (size_t)(3 + s) * 640000ull;
    const float* Bt = base + (size_t)s * 640000ull;
    const int tid = threadIdx.x;

    __shared__ __align__(16) __bf16 Ah[128][56];
    __shared__ __align__(16) __bf16 Al[128][56];
    __shared__ __align__(16) __bf16 Bh[128][56];
    __shared__ __align__(16) __bf16 Bl[128][56];

    const int am  = tid >> 1;
    const int akb = (tid & 1) * 16;
    const int qA  = q0 + am;
    const int tB  = t0 + am;
    const float* arow = Aq + (size_t)qA * 1600 + akb;
    const float* brow = Bt + (size_t)tB * 1600 + akb;
    const bool aok = qA < 400;
    const bool bok = tB < 400;

    const int lane = tid & 63;
    const int wv = tid >> 6;
    const int wr = (wv >> 1) * 64, wc = (wv & 1) * 64;
    const int lr = lane & 15;
    const int lk = (lane >> 4) * 8;

    f32x4 acc[4][4];
#pragma unroll
    for (int i = 0; i < 4; i++)
#pragma unroll
        for (int j = 0; j < 4; j++) acc[i][j] = (f32x4){0.f, 0.f, 0.f, 0.f};

    float4 areg[4], brg[4];
    auto loadAB = [&](int kc) {
#pragma unroll
        for (int q = 0; q < 4; q++) {
            areg[q] = aok ? ld4(arow + kc + q * 4) : make_float4(0.f, 0.f, 0.f, 0.f);
            brg[q]  = bok ? ld4(brow + kc + q * 4) : make_float4(0.f, 0.f, 0.f, 0.f);
        }
    };

    loadAB(0);

    for (int k0 = 0; k0 < 1600; k0 += 32) {
        {
            bf16x8 h0, h1, l0, l1;
#pragma unroll
            for (int q = 0; q < 4; q++) {
                const float vs0 = areg[q].x, vs1 = areg[q].y, vs2 = areg[q].z, vs3 = areg[q].w;
                __bf16 hh; const int ib = q * 4;
#define CVTA(c, val) { hh = (__bf16)(val); __bf16 ll = (__bf16)((val) - (float)hh); \
    if (ib + c < 8) { h0[ib + c] = hh; l0[ib + c] = ll; } else { h1[ib + c - 8] = hh; l1[ib + c - 8] = ll; } }
                CVTA(0, vs0) CVTA(1, vs1) CVTA(2, vs2) CVTA(3, vs3)
#undef CVTA
            }
            *(bf16x8*)&Ah[am][akb]     = h0;
            *(bf16x8*)&Ah[am][akb + 8] = h1;
            *(bf16x8*)&Al[am][akb]     = l0;
            *(bf16x8*)&Al[am][akb + 8] = l1;
        }
        {
            bf16x8 h0, h1, l0, l1;
#pragma unroll
            for (int q = 0; q < 4; q++) {
                const float vs0 = brg[q].x, vs1 = brg[q].y, vs2 = brg[q].z, vs3 = brg[q].w;
                __bf16 hh; const int ib = q * 4;
#define CVTB(c, val) { hh = (__bf16)(val); __bf16 ll = (__bf16)((val) - (float)hh); \
    if (ib + c < 8) { h0[ib + c] = hh; l0[ib + c] = ll; } else { h1[ib + c - 8] = hh; l1[ib + c - 8] = ll; } }
                CVTB(0, vs0) CVTB(1, vs1) CVTB(2, vs2) CVTB(3, vs3)
#undef CVTB
            }
            *(bf16x8*)&Bh[am][akb]     = h0;
            *(bf16x8*)&Bh[am][akb + 8] = h1;
            *(bf16x8*)&Bl[am][akb]     = l0;
            *(bf16x8*)&Bl[am][akb + 8] = l1;
        }
        __syncthreads();

        const int kn = k0 + 32;
        if (kn < 1600) loadAB(kn);

        bf16x8 fbh[4], fbl[4];
#pragma unroll
        for (int fj = 0; fj < 4; fj++) {
            fbh[fj] = *(bf16x8*)&Bh[wc + fj * 16 + lr][lk];
            fbl[fj] = *(bf16x8*)&Bl[wc + fj * 16 + lr][lk];
        }
#pragma unroll
        for (int fi = 0; fi < 4; fi++) {
            bf16x8 fah = *(bf16x8*)&Ah[wr + fi * 16 + lr][lk];
            bf16x8 fal = *(bf16x8*)&Al[wr + fi * 16 + lr][lk];
#pragma unroll
            for (int fj = 0; fj < 4; fj++) {
                acc[fi][fj] = __builtin_amdgcn_mfma_f32_16x16x32_bf16(fah, fbh[fj], acc[fi][fj], 0, 0, 0);
                acc[fi][fj] = __builtin_amdgcn_mfma_f32_16x16x32_bf16(fah, fbl[fj], acc[fi][fj], 0, 0, 0);
                acc[fi][fj] = __builtin_amdgcn_mfma_f32_16x16x32_bf16(fal, fbh[fj], acc[fi][fj], 0, 0, 0);
            }
        }
        __syncthreads();
    }

    const int rb = (lane >> 4) * 4;
    const float al = alphat[s];
    float* aTp = aT + (size_t)idx * 160000ull;
    const float* a0p = att0t + (size_t)s * 160000ull;

#pragma unroll
    for (int fi = 0; fi < 4; fi++) {
        const int qb = q0 + wr + fi * 16 + rb;
#pragma unroll
        for (int fj = 0; fj < 4; fj++) {
            const int t = t0 + wc + fj * 16 + lr;
            if (t >= 400) continue;
#pragma unroll
            for (int r = 0; r < 4; r++) {
                const int q = qb + r;
                if (q >= 400) continue;
                aTp[(size_t)q * 400 + t] =
                    tanhf(acc[fi][fj][r] * (1.f / 1600.f)) * al + a0p[(size_t)t * 400 + q];
            }
        }
    }
}

// ---------------------------------------------------------------------------
// Spatial scores, partial K: 200 chunks of 128 rows. Grid (200, 3, G).  [R0]
// ---------------------------------------------------------------------------
__global__ __launch_bounds__(256)
void scores_s_partial(const float* __restrict__ qk, float* __restrict__ part)
{
    const int chunk = blockIdx.x, s = blockIdx.y, ln = blockIdx.z;
    const float* qsec = qk + ((size_t)ln * 384 + s * 64) * PP + (size_t)chunk * 3200;
    const float* ksec = qk + ((size_t)ln * 384 + (3 + s) * 64) * PP + (size_t)chunk * 3200;
    __shared__ float QL[3200];
    __shared__ float KL[3200];
    const int tid = threadIdx.x;
    for (int i = tid; i < 3200; i += 256) {
        QL[i] = qsec[i];
        KL[i] = ksec[i];
    }
    __syncthreads();
    const int o0 = tid, o1 = tid + 256, o2 = tid + 512;
    const int u0 = o0 / 25, v0 = o0 % 25;
    const int u1 = o1 / 25, v1 = o1 % 25;
    const int u2 = o2 / 25, v2 = o2 % 25;
    float a0 = 0.f, a1 = 0.f, a2 = 0.f;
#pragma unroll 8
    for (int r = 0; r < 128; r++) {
        int ro = r * 25;
        a0 = fmaf(QL[ro + u0], KL[ro + v0], a0);
        a1 = fmaf(QL[ro + u1], KL[ro + v1], a1);
        if (tid < 113) a2 = fmaf(QL[ro + u2], KL[ro + v2], a2);
    }
    float* pp = part + (((size_t)(ln * 3 + s)) * 200 + chunk) * 625;
    pp[o0] = a0;
    pp[o1] = a1;
    if (tid < 113) pp[o2] = a2;
}

// grid.x = 3*G blocks (idx = ln*3+s), 640 threads. Sums 200 partials.  [R0]
__global__ void scores_s_final(const float* __restrict__ part,
                               const float* __restrict__ alphas,
                               const float* __restrict__ att0s,
                               float* __restrict__ atts)
{
    const int idx = blockIdx.x;
    const int s = idx % 3;
    const int o = threadIdx.x;
    if (o >= 625) return;
    const float* pb = part + (size_t)idx * 200 * 625 + o;
    float sum = 0.f;
#pragma unroll 8
    for (int i = 0; i < 200; i++) sum += pb[(size_t)i * 625];
    atts[(size_t)idx * 625 + o] = tanhf(sum * (1.f / 25600.f)) * alphas[s] + att0s[s * 625 + o];
}

// ---------------------------------------------------------------------------
// Spatial apply (one s). Grid (200, G).  [R0]
// ---------------------------------------------------------------------------
__global__ __launch_bounds__(256)
void apply_s_kernel(const float* __restrict__ x0, const float* __restrict__ x1,
                    const float* __restrict__ atts, float* __restrict__ z,
                    int n0, int s)
{
    const int ln = blockIdx.y;
    const int ns = n0 + ln;
    const int tid = threadIdx.x;
    __shared__ float attL[700];   // 25*28 padded
    for (int i = tid; i < 700; i += 256) attL[i] = 0.f;
    __syncthreads();
    for (int i = tid; i < 625; i += 256) {
        int v = i / 25, w = i % 25;
        attL[v * 28 + w] = atts[(size_t)ln * 1875 + s * 625 + i];
    }
    __syncthreads();
    const float* xp = (ns < 4) ? x0 + (size_t)ns * SAMP : x1 + (size_t)(ns - 4) * SAMP;
    const int r0 = (blockIdx.x * 256 + tid) * 2;   // even; both rows share c
    const float* xr0 = xp + (size_t)r0 * 25;
    float xr[2][25];
#pragma unroll
    for (int i = 0; i < 2; i++)
#pragma unroll
        for (int v = 0; v < 25; v++) xr[i][v] = xr0[i * 25 + v];
    const int c0 = r0 / 400, t0 = r0 % 400;

    float4 acc0[7], acc1[7];
#pragma unroll
    for (int w4 = 0; w4 < 7; w4++) {
        acc0[w4] = make_float4(0.f, 0.f, 0.f, 0.f);
        acc1[w4] = make_float4(0.f, 0.f, 0.f, 0.f);
    }
#pragma unroll
    for (int v = 0; v < 25; v++) {
        const float4* arow = (const float4*)&attL[v * 28];
        float xv0 = xr[0][v], xv1 = xr[1][v];
#pragma unroll
        for (int w4 = 0; w4 < 7; w4++) {
            float4 a = arow[w4];
            acc0[w4].x = fmaf(xv0, a.x, acc0[w4].x);
            acc0[w4].y = fmaf(xv0, a.y, acc0[w4].y);
            acc0[w4].z = fmaf(xv0, a.z, acc0[w4].z);
            acc0[w4].w = fmaf(xv0, a.w, acc0[w4].w);
            acc1[w4].x = fmaf(xv1, a.x, acc1[w4].x);
            acc1[w4].y = fmaf(xv1, a.y, acc1[w4].y);
            acc1[w4].z = fmaf(xv1, a.z, acc1[w4].z);
            acc1[w4].w = fmaf(xv1, a.w, acc1[w4].w);
        }
    }
    float* zp = z + (size_t)ln * SAMP + (size_t)c0 * PP + (size_t)t0 * 25;
#pragma unroll
    for (int w4 = 0; w4 < 7; w4++) {
        int wb = w4 * 4;
        if (wb + 0 < 25) zp[wb + 0] = acc0[w4].x;
        if (wb + 1 < 25) zp[wb + 1] = acc0[w4].y;
        if (wb + 2 < 25) zp[wb + 2] = acc0[w4].z;
        if (wb + 3 < 25) zp[wb + 3] = acc0[w4].w;
    }
#pragma unroll
    for (int w4 = 0; w4 < 7; w4++) {
        int wb = w4 * 4;
        if (wb + 0 < 25) zp[25 + wb + 0] = acc1[w4].x;
        if (wb + 1 < 25) zp[25 + wb + 1] = acc1[w4].y;
        if (wb + 2 < 25) zp[25 + wb + 2] = acc1[w4].z;
        if (wb + 3 < 25) zp[25 + wb + 3] = acc1[w4].w;
    }
}

// ---------------------------------------------------------------------------
extern "C" void kernel_launch(void* const* d_in, const int* in_sizes, int n_in,
                              void* d_out, int out_size, void* d_ws, size_t ws_size,
                              hipStream_t stream)
{
    const float* x    = (const float*)d_in[0];
    const float* x1   = (const float*)d_in[1];
    const float* pe_s = (const float*)d_in[2];
    const float* pe_t = (const float*)d_in[3];
    const float* Wsi  = (const float*)d_in[4];
    const float* bsi  = (const float*)d_in[5];
    const float* alphas = (const float*)d_in[6];
    const float* att0s  = (const float*)d_in[7];
    const float* Wso  = (const float*)d_in[8];
    const float* bso  = (const float*)d_in[9];
    const float* gso  = (const float*)d_in[10];
    const float* beso = (const float*)d_in[11];
    const float* Wsf  = (const float*)d_in[12];
    const float* bsf  = (const float*)d_in[13];
    const float* gsf  = (const float*)d_in[14];
    const float* besf = (const float*)d_in[15];
    const float* Wti  = (const float*)d_in[16];
    const float* bti  = (const float*)d_in[17];
    const float* alphat = (const float*)d_in[18];
    const float* att0t  = (const float*)d_in[19];
    const float* Wto  = (const float*)d_in[20];
    const float* bto  = (const float*)d_in[21];
    const float* gto  = (const float*)d_in[22];
    const float* beto = (const float*)d_in[23];
    const float* Wtf  = (const float*)d_in[24];
    const float* btf  = (const float*)d_in[25];
    const float* gtf  = (const float*)d_in[26];
    const float* betf = (const float*)d_in[27];

    float* outp = (float*)d_out;
    const float* outpB = outp + 4ull * SAMP;   // samples 4..7 view

    int G = 1;
    for (int g = 8; g >= 1; g >>= 1) {
        if ((size_t)g * 27587500ull <= ws_size) { G = g; break; }
    }

    float* A   = (float*)d_ws;                       // qk / qkT, then h overlay
    float* Zs  = A  + (size_t)G * 3840000ull;        // z slice / score partials
    float* aT  = Zs + (size_t)G * 2560000ull;        // temporal att
    float* sp  = aT + (size_t)G * 480000ull;         // (unused, kept for layout)
    float* as  = sp + (size_t)G * 15000ull;          // spatial att

    dim3 blk(256);
    for (int n0 = 0; n0 < 8; n0 += G) {
        dim3 gIn(79, 3, G), gOut(79, 2, G);

        // ---- spatial stage (input x / x1) ----
        gemm_mfma<0, true, true, false><<<gIn, blk, 0, stream>>>(
            Wsi, 256, bsi, nullptr, nullptr, x, x1, nullptr, pe_s,
            nullptr, nullptr, A, n0, 384, 256);
        scores_s_partial<<<dim3(200, 3, G), blk, 0, stream>>>(A, Zs);
        scores_s_final<<<dim3(3 * G), dim3(640), 0, stream>>>(Zs, alphas, att0s, as);
        for (int s = 0; s < 3; s++) {
            apply_s_kernel<<<dim3(200, G), blk, 0, stream>>>(x, x1, as, Zs, n0, s);
            if (s == 0)
                gemm_mfma<2, false, false, false><<<gOut, blk, 0, stream>>>(
                    Wso + s * 256, 768, nullptr, nullptr, nullptr, nullptr, nullptr, Zs,
                    nullptr, nullptr, nullptr, A, n0, 256, 256);
            else if (s == 1)
                gemm_mfma<3, false, false, false><<<gOut, blk, 0, stream>>>(
                    Wso + s * 256, 768, nullptr, nullptr, nullptr, nullptr, nullptr, Zs,
                    nullptr, nullptr, nullptr, A, n0, 256, 256);
            else
                gemm_mfma<4, false, false, false><<<gOut, blk, 0, stream>>>(
                    Wso + s * 256, 768, bso, gso, beso, nullptr, nullptr, Zs,
                    nullptr, x, x1, A, n0, 256, 256);
        }
        gemm_mfma<1, false, false, true><<<gOut, blk, 0, stream>>>(
            Wsf, 256, bsf, gsf, besf, nullptr, nullptr, A, nullptr,
            x, x1, outp, n0, 256, 256);

        // ---- temporal stage (input d_out, in place) ----
        gemm_mfma<5, true, true, false><<<gIn, blk, 0, stream>>>(
            Wti, 256, bti, nullptr, nullptr, outp, outpB, nullptr, pe_t,
            nullptr, nullptr, A, n0, 384, 256);
        scores_t_mfma<<<dim3(16, 3 * G), blk, 0, stream>>>(A, alphat, att0t, aT);
        for (int s = 0; s < 3; s++) {
            apply_t_mfma<<<dim3(50, 4, G), blk, 0, stream>>>(outp, aT, Zs, n0, s);
            if (s == 0)
                gemm_mfma<2, false, false, false><<<gOut, blk, 0, stream>>>(
                    Wto + s * 256, 768, nullptr, nullptr, nullptr, nullptr, nullptr, Zs,
                    nullptr, nullptr, nullptr, A, n0, 256, 256);
            else if (s == 1)
                gemm_mfma<3, false, false, false><<<gOut, blk, 0, stream>>>(
                    Wto + s * 256, 768, nullptr, nullptr, nullptr, nullptr, nullptr, Zs,
                    nullptr, nullptr, nullptr, A, n0, 256, 256);
            else
                gemm_mfma<4, false, false, false><<<gOut, blk, 0, stream>>>(
                    Wto + s * 256, 768, bto, gto, beto, nullptr, nullptr, Zs,
                    nullptr, outp, outpB, A, n0, 256, 256);
        }
        gemm_mfma<1, false, false, true><<<gOut, blk, 0, stream>>>(
            Wtf, 256, btf, gtf, betf, nullptr, nullptr, A, nullptr,
            outp, outpB, outp, n0, 256, 256);
    }
}